// Round 4
// baseline (718.277 us; speedup 1.0000x reference)
//
#include <hip/hip_runtime.h>

#define NMETA 64
#define MSUB 1024
#define NNODES 65536          // NMETA*MSUB
#define D 128
#define DOUT 64
#define NEDGES 1048576
#define COLS 131072           // MSUB*D
#define BCAP 5120             // LDS capacity per bucket (mean 4096, sigma ~64)
#define YCH (NNODES * 32)     // shorts per Y chunk plane (32 cols = 64B/node = 4 MiB)

typedef __attribute__((ext_vector_type(8))) short bf8_t;   // 8 bf16 = 4 VGPRs
typedef __attribute__((ext_vector_type(4))) float f4_t;
typedef __attribute__((ext_vector_type(2))) float f2_t;    // -> v_pk_fma_f32
typedef __attribute__((ext_vector_type(4))) unsigned ui4_t; // nontemporal-safe 16B

__device__ inline unsigned short bfr(float x) {            // fp32 -> bf16 RNE
    unsigned u = __builtin_bit_cast(unsigned, x);
    u += 0x7fffu + ((u >> 16) & 1u);
    return (unsigned short)(u >> 16);
}
__device__ inline float b2f(unsigned short h) {
    return __builtin_bit_cast(float, (unsigned)h << 16);
}
__device__ inline f2_t up2(unsigned u) {                   // 2 bf16 -> 2 fp32
    f2_t r;
    r[0] = __builtin_bit_cast(float, u << 16);
    r[1] = __builtin_bit_cast(float, u & 0xffff0000u);
    return r;
}

// ------------------------------------------------------- CSR via 256-bucket radix
__global__ __launch_bounds__(256) void k_bhist(const int* __restrict__ dst,
                                               int* __restrict__ whist) {
    __shared__ int c[256];
    int t = threadIdx.x, w = blockIdx.x;
    c[t] = 0;
    __syncthreads();
    const int* dp = dst + w * 4096;
    for (int k = 0; k < 16; ++k) atomicAdd(&c[dp[k * 256 + t] >> 8], 1);
    __syncthreads();
    whist[t * 256 + w] = c[t];
}

__global__ __launch_bounds__(256) void k_bscan(int* __restrict__ whist,
                                               int* __restrict__ bbase) {
    __shared__ int sh[256];
    int t = threadIdx.x;
    int run = 0;
    for (int w = 0; w < 256; ++w) {
        int v = whist[t * 256 + w];
        whist[t * 256 + w] = run;
        run += v;
    }
    sh[t] = run;
    __syncthreads();
    for (int d = 1; d < 256; d <<= 1) {
        int x = (t >= d) ? sh[t - d] : 0;
        __syncthreads();
        sh[t] += x;
        __syncthreads();
    }
    bbase[t] = sh[t] - run;
    if (t == 255) bbase[256] = NEDGES;
}

__global__ __launch_bounds__(256) void k_bscatter(const int* __restrict__ src,
                                                  const int* __restrict__ dst,
                                                  const int* __restrict__ bbase,
                                                  const int* __restrict__ whist,
                                                  unsigned* __restrict__ tmp) {
    __shared__ int cur[256];
    __shared__ int base[256];
    int t = threadIdx.x, w = blockIdx.x;
    cur[t] = 0;
    base[t] = bbase[t] + whist[t * 256 + w];
    __syncthreads();
    const int* dp = dst + w * 4096;
    const int* sp = src + w * 4096;
    for (int k = 0; k < 16; ++k) {
        int d = dp[k * 256 + t], s = sp[k * 256 + t];
        int b = d >> 8;
        int lr = atomicAdd(&cur[b], 1);
        tmp[base[b] + lr] = ((unsigned)(d & 255) << 16) | (unsigned)s;
    }
}

__global__ __launch_bounds__(256) void k_bcsr(const unsigned* __restrict__ tmp,
                                              const int* __restrict__ bbase,
                                              int* __restrict__ offs,
                                              float* __restrict__ dinv,
                                              unsigned short* __restrict__ csr16) {
    __shared__ unsigned pairs[BCAP];
    __shared__ unsigned short image[BCAP];
    __shared__ int cnt[256], cur[256], sh[256];
    int t = threadIdx.x, b = blockIdx.x;
    int base = bbase[b], n = bbase[b + 1] - base;
    for (int i = t; i < n; i += 256) pairs[i] = tmp[base + i];
    cnt[t] = 0;
    __syncthreads();
    for (int i = t; i < n; i += 256) atomicAdd(&cnt[pairs[i] >> 16], 1);
    __syncthreads();
    int c = cnt[t];
    sh[t] = c;
    __syncthreads();
    for (int d = 1; d < 256; d <<= 1) {
        int x = (t >= d) ? sh[t - d] : 0;
        __syncthreads();
        sh[t] += x;
        __syncthreads();
    }
    int excl = sh[t] - c;
    cur[t] = excl;
    offs[b * 256 + t] = base + excl;
    dinv[b * 256 + t] = rsqrtf((float)(c + 1));
    if (b == 255 && t == 255) offs[65536] = NEDGES;
    __syncthreads();
    for (int i = t; i < n; i += 256) {
        unsigned p = pairs[i];
        int pos = atomicAdd(&cur[p >> 16], 1);
        image[pos] = (unsigned short)(p & 0xffffu);
    }
    __syncthreads();
    for (int i = t; i < n; i += 256) csr16[base + i] = image[i];
}

// --------------------------------------------- setup: adjpow + cvt_w (x handled by layer 0)
__global__ __launch_bounds__(256) void k_setup(const float* __restrict__ A,
                                               unsigned short* __restrict__ Ab,
                                               const float* __restrict__ gcnW,
                                               const float* __restrict__ W1,
                                               const float* __restrict__ W2,
                                               unsigned short* __restrict__ Wt) {
    int blk = blockIdx.x, t = threadIdx.x;
    if (blk == 0) {
        __shared__ float As[4096];
        __shared__ float Bs[4096];
        for (int q = 0; q < 16; ++q) As[t + 256 * q] = A[t + 256 * q];
        __syncthreads();
        for (int q = 0; q < 16; ++q) {
            int idx = t + 256 * q;
            int n = idx >> 6, j = idx & 63;
            Ab[idx] = bfr(As[idx]);
            float acc = 0.f;
            for (int k = 0; k < 64; ++k) acc += As[n * 64 + k] * As[k * 64 + j];
            Bs[idx] = acc;
            Ab[4096 + idx] = bfr(acc);
        }
        __syncthreads();
        for (int q = 0; q < 16; ++q) {
            int idx = t + 256 * q;
            int n = idx >> 6, j = idx & 63;
            float acc = 0.f;
            for (int k = 0; k < 64; ++k) acc += Bs[n * 64 + k] * As[k * 64 + j];
            Ab[8192 + idx] = bfr(acc);
        }
    } else {
        int b2 = blk - 1;
        int m = b2 >> 6;
        int idx = (b2 & 63) * 256 + t;
        const float* src;
        int N = 128;
        if (m < 12)       src = gcnW + m * 16384;
        else if (m == 12) src = W1;
        else { src = W2; N = 64; if (idx >= 8192) return; }
        int n = idx >> 7, k = idx & 127;
        Wt[m * 16384 + idx] = bfr(src[k * N + n]);
    }
}

// ------------------------------------------------- fused layer: mix + gemm
// One block per sub-node m. Y = dinv ⊙ sum_z A_z @ (X[:,m,:] @ W_z), A_0 = I.
// Output is written CHUNK-MAJOR: 4 planes of 32 cols, plane c = Y + c*YCH,
// node u's 64B chunk row at Yc + u*32 shorts. wave == chunk here (c0=wave*32).
// Nontemporal stores: Y is consumed by a different XCD's pinned L2.
#define TS 130
template <bool INF32>
__global__ __launch_bounds__(256) void k_layer(const unsigned short* __restrict__ X,
                                               const float* __restrict__ Xf,
                                               const unsigned short* __restrict__ Ab,
                                               const unsigned short* __restrict__ Wt4,
                                               const float* __restrict__ dinv,
                                               unsigned short* __restrict__ Y) {
    __shared__ unsigned short LB[3 * 64 * TS];   // 48.75 KB; aliased X stage first
    __shared__ float dsh[64];
    int t = threadIdx.x;
    int m = blockIdx.x;
    int wave = t >> 6, lane = t & 63;
    int l16 = lane & 15, kg = lane >> 4;
    int c0 = wave * 32;

    if (t < 64) dsh[t] = dinv[(long)t * MSUB + m];

    // stage X[:, m, :] as [row][128] (row stride 256B, 16B-aligned)
#pragma unroll
    for (int it = 0; it < 4; ++it) {
        int slot = it * 256 + t;
        int row = slot >> 4, ch = slot & 15;
        if (INF32) {
            const float* xp = Xf + ((long)row * MSUB + m) * D + ch * 8;
            float4 va = *(const float4*)xp;
            float4 vb = *(const float4*)(xp + 4);
            uint4 pk;
            pk.x = ((unsigned)bfr(va.y) << 16) | bfr(va.x);
            pk.y = ((unsigned)bfr(va.w) << 16) | bfr(va.z);
            pk.z = ((unsigned)bfr(vb.y) << 16) | bfr(vb.x);
            pk.w = ((unsigned)bfr(vb.w) << 16) | bfr(vb.z);
            *(uint4*)&LB[row * 128 + ch * 8] = pk;
        } else {
            *(uint4*)&LB[row * 128 + ch * 8] =
                *(const uint4*)(X + ((long)row * MSUB + m) * D + ch * 8);
        }
    }
    __syncthreads();

    // snapshot A-operand fragments of X_m (all 4 m-tiles, full K=128)
    bf8_t xa[4][4];
#pragma unroll
    for (int mt = 0; mt < 4; ++mt)
#pragma unroll
        for (int kb = 0; kb < 4; ++kb)
            xa[mt][kb] = *(const bf8_t*)&LB[(mt * 16 + l16) * 128 + kb * 32 + kg * 8];
    __syncthreads();   // everyone done reading X stage before T overwrites it

    f4_t zero4 = {0.f, 0.f, 0.f, 0.f};

    // phase 1a: T_0 = X_m @ W_0 -> registers
    f4_t accT0[4][2];
#pragma unroll
    for (int mt = 0; mt < 4; ++mt)
#pragma unroll
        for (int nt = 0; nt < 2; ++nt) accT0[mt][nt] = zero4;
#pragma unroll
    for (int kb = 0; kb < 4; ++kb)
#pragma unroll
        for (int nt = 0; nt < 2; ++nt) {
            bf8_t b = *(const bf8_t*)(Wt4 + (long)(c0 + nt * 16 + l16) * 128 +
                                      kb * 32 + kg * 8);
#pragma unroll
            for (int mt = 0; mt < 4; ++mt)
                accT0[mt][nt] = __builtin_amdgcn_mfma_f32_16x16x32_bf16(
                    xa[mt][kb], b, accT0[mt][nt], 0, 0, 0);
        }

    // phase 1b: T_z = X_m @ W_z (z=1..3) -> LDS (bf16), this wave's 32 cols
#pragma unroll
    for (int z = 1; z < 4; ++z) {
        f4_t acc[4][2];
#pragma unroll
        for (int mt = 0; mt < 4; ++mt)
#pragma unroll
            for (int nt = 0; nt < 2; ++nt) acc[mt][nt] = zero4;
        const unsigned short* wp = Wt4 + z * 16384;
#pragma unroll
        for (int kb = 0; kb < 4; ++kb)
#pragma unroll
            for (int nt = 0; nt < 2; ++nt) {
                bf8_t b = *(const bf8_t*)(wp + (long)(c0 + nt * 16 + l16) * 128 +
                                          kb * 32 + kg * 8);
#pragma unroll
                for (int mt = 0; mt < 4; ++mt)
                    acc[mt][nt] = __builtin_amdgcn_mfma_f32_16x16x32_bf16(
                        xa[mt][kb], b, acc[mt][nt], 0, 0, 0);
            }
#pragma unroll
        for (int mt = 0; mt < 4; ++mt)
#pragma unroll
            for (int nt = 0; nt < 2; ++nt)
#pragma unroll
                for (int r = 0; r < 4; ++r)
                    LB[((z - 1) * 64 + mt * 16 + kg * 4 + r) * TS +
                       c0 + nt * 16 + l16] = bfr(acc[mt][nt][r]);
    }
    // no barrier: each wave reads only its own column slab of T

    // phase 2: Y_slab = T_0 + sum_i A_i @ T_i
    f4_t acc2[4][2];
#pragma unroll
    for (int mt = 0; mt < 4; ++mt)
#pragma unroll
        for (int nt = 0; nt < 2; ++nt) acc2[mt][nt] = zero4;
#pragma unroll
    for (int i = 0; i < 3; ++i)
#pragma unroll
        for (int kb = 0; kb < 2; ++kb) {
            bf8_t af[4];
#pragma unroll
            for (int mt = 0; mt < 4; ++mt)
                af[mt] = *(const bf8_t*)(Ab + i * 4096 + (mt * 16 + l16) * 64 +
                                         kb * 32 + kg * 8);
#pragma unroll
            for (int nt = 0; nt < 2; ++nt) {
                bf8_t b;
#pragma unroll
                for (int jj = 0; jj < 8; ++jj)
                    b[jj] = (short)LB[(i * 64 + kb * 32 + kg * 8 + jj) * TS +
                                      c0 + nt * 16 + l16];
#pragma unroll
                for (int mt = 0; mt < 4; ++mt)
                    acc2[mt][nt] = __builtin_amdgcn_mfma_f32_16x16x32_bf16(
                        af[mt], b, acc2[mt][nt], 0, 0, 0);
            }
        }

    // epilogue: scale by dinv, write chunk-major plane (chunk == wave)
    unsigned short* Yc = Y + (size_t)wave * YCH;
#pragma unroll
    for (int mt = 0; mt < 4; ++mt)
#pragma unroll
        for (int nt = 0; nt < 2; ++nt)
#pragma unroll
            for (int r = 0; r < 4; ++r) {
                int row = mt * 16 + kg * 4 + r;
                int cic = nt * 16 + l16;
                float v = (acc2[mt][nt][r] + accT0[mt][nt][r]) * dsh[row];
                __builtin_nontemporal_store(
                    bfr(v), Yc + ((long)row * MSUB + m) * 32 + cic);
            }
}

// -------------------------------------------------------------- propagation
// Chunk-pinned gather, ONE dst per wave: 16 edge slots x 4 col-lanes (16B each).
// A single wave-instruction gathers 16 edges' 64B chunk rows; deg~16 -> ~1 main
// iteration, no intra-wave dst divergence. Reduction = 4 shfl_xor butterflies
// over the slot bits; lanes 0-3 (slot 0) hold the 64B result.
__global__ __launch_bounds__(256) void k_prop(const unsigned short* __restrict__ Y,
                                              const int* __restrict__ offs,
                                              const unsigned short* __restrict__ csr,
                                              const float* __restrict__ dinv,
                                              const float* __restrict__ bias4,
                                              unsigned short* __restrict__ Xout) {
    int t = threadIdx.x;
    int wave = t >> 6, lane = t & 63;
    int slot = lane >> 2;                         // 16 edge slots
    int l = lane & 3;                             // 4 x 16B col lanes (64B row)
    int c = blockIdx.x & 3;                       // chunk (XCD-pinned)
    int v = (blockIdx.x >> 2) * 4 + wave;         // dst node (one per wave)
    const uint4* Yc = (const uint4*)(Y + (size_t)c * YCH);

    int e0 = offs[v], e1 = offs[v + 1];
    f2_t acc2[4];
#pragma unroll
    for (int k = 0; k < 4; ++k) acc2[k] = (f2_t){0.f, 0.f};

    int e = e0 + slot;
    for (; e + 16 < e1; e += 32) {               // 2-deep for deg > 16
        int u0 = csr[e], u1 = csr[e + 16];
        uint4 y0 = Yc[(long)u0 * 4 + l];
        uint4 y1 = Yc[(long)u1 * 4 + l];
        acc2[0] += up2(y0.x) + up2(y1.x);
        acc2[1] += up2(y0.y) + up2(y1.y);
        acc2[2] += up2(y0.z) + up2(y1.z);
        acc2[3] += up2(y0.w) + up2(y1.w);
    }
    if (e < e1) {
        int u = csr[e];
        uint4 y = Yc[(long)u * 4 + l];
        acc2[0] += up2(y.x);
        acc2[1] += up2(y.y);
        acc2[2] += up2(y.z);
        acc2[3] += up2(y.w);
    }
    float acc[8];
#pragma unroll
    for (int k = 0; k < 4; ++k) { acc[2 * k] = acc2[k][0]; acc[2 * k + 1] = acc2[k][1]; }
#pragma unroll
    for (int k = 0; k < 8; ++k) {                // butterfly over the 4 slot bits
        acc[k] += __shfl_xor(acc[k], 4, 64);
        acc[k] += __shfl_xor(acc[k], 8, 64);
        acc[k] += __shfl_xor(acc[k], 16, 64);
        acc[k] += __shfl_xor(acc[k], 32, 64);
    }
    if (slot == 0) {
        float dv = dinv[v];
        uint4 s = Yc[(long)v * 4 + l];            // pre-scaled self row chunk
        f2_t s2[4] = {up2(s.x), up2(s.y), up2(s.z), up2(s.w)};
        float bs[8];
#pragma unroll
        for (int k = 0; k < 8; ++k) bs[k] = 0.f;
#pragma unroll
        for (int p = 0; p < 4; ++p) {
            float4 blo = *(const float4*)(bias4 + p * 128 + c * 32 + l * 8);
            float4 bhi = *(const float4*)(bias4 + p * 128 + c * 32 + l * 8 + 4);
            bs[0] += blo.x; bs[1] += blo.y; bs[2] += blo.z; bs[3] += blo.w;
            bs[4] += bhi.x; bs[5] += bhi.y; bs[6] += bhi.z; bs[7] += bhi.w;
        }
        unsigned r[8];
#pragma unroll
        for (int k = 0; k < 8; ++k) {
            float sf = s2[k / 2][k % 2];
            r[k] = bfr(fmaxf(dv * (acc[k] + sf) + bs[k], 0.f));
        }
        ui4_t pk;
        pk.x = (r[1] << 16) | r[0];
        pk.y = (r[3] << 16) | r[2];
        pk.z = (r[5] << 16) | r[4];
        pk.w = (r[7] << 16) | r[6];
        __builtin_nontemporal_store(
            pk, (ui4_t*)(Xout + (long)v * 128 + c * 32 + l * 8));
    }
}

// ---------------------------------------------------- fused MLP: relu(X@W1+b1)@W2+b2
// 128 rows/block, H kept in LDS (stride 136 shorts: b128 reads <=2-way).
// Each wave computes its own 32 H rows then consumes them -> no barriers.
#define HST 136
__global__ __launch_bounds__(256) void k_mlp(const unsigned short* __restrict__ X,
                                             const unsigned short* __restrict__ Wt, // +12*16384 = W1t, +13*16384 = W2t
                                             const float* __restrict__ b1,
                                             const float* __restrict__ b2,
                                             float* __restrict__ out) {
    __shared__ unsigned short H[128 * HST];      // 34.8 KB
    int wave = threadIdx.x >> 6, lane = threadIdx.x & 63;
    int l16 = lane & 15, kg = lane >> 4;
    long row0 = (long)blockIdx.x * 128 + wave * 32;
    int hb = wave * 32 * HST;

    bf8_t a[2][4];
    const unsigned short* xp = X + row0 * 128 + kg * 8;
#pragma unroll
    for (int kb = 0; kb < 4; ++kb) {
        a[0][kb] = *(const bf8_t*)(xp + (long)l16 * 128 + kb * 32);
        a[1][kb] = *(const bf8_t*)(xp + (long)(l16 + 16) * 128 + kb * 32);
    }
    f4_t zero4 = {0.f, 0.f, 0.f, 0.f};
    f4_t acc[2][8];
#pragma unroll
    for (int mt = 0; mt < 2; ++mt)
#pragma unroll
        for (int nt = 0; nt < 8; ++nt) acc[mt][nt] = zero4;

    const unsigned short* wp = Wt + 12 * 16384 + (long)l16 * 128 + kg * 8;
#pragma unroll
    for (int kb = 0; kb < 4; ++kb)
#pragma unroll
        for (int nt = 0; nt < 8; ++nt) {
            bf8_t b = *(const bf8_t*)(wp + nt * 16 * 128 + kb * 32);
            acc[0][nt] = __builtin_amdgcn_mfma_f32_16x16x32_bf16(a[0][kb], b, acc[0][nt], 0, 0, 0);
            acc[1][nt] = __builtin_amdgcn_mfma_f32_16x16x32_bf16(a[1][kb], b, acc[1][nt], 0, 0, 0);
        }

    // epilogue 1: H = relu(acc + b1) -> LDS (wave-local rows)
#pragma unroll
    for (int nt = 0; nt < 8; ++nt) {
        float bv = b1[nt * 16 + l16];
#pragma unroll
        for (int mt = 0; mt < 2; ++mt)
#pragma unroll
            for (int r = 0; r < 4; ++r) {
                int row = mt * 16 + kg * 4 + r;
                H[hb + row * HST + nt * 16 + l16] = bfr(fmaxf(acc[mt][nt][r] + bv, 0.f));
            }
    }

    // second GEMM: out = H @ W2 + b2  (A-frags from LDS, same-wave rows)
    bf8_t h2[2][4];
#pragma unroll
    for (int kb = 0; kb < 4; ++kb) {
        h2[0][kb] = *(const bf8_t*)&H[hb + l16 * HST + kb * 32 + kg * 8];
        h2[1][kb] = *(const bf8_t*)&H[hb + (l16 + 16) * HST + kb * 32 + kg * 8];
    }
    f4_t acc2[2][4];
#pragma unroll
    for (int mt = 0; mt < 2; ++mt)
#pragma unroll
        for (int nt = 0; nt < 4; ++nt) acc2[mt][nt] = zero4;
    const unsigned short* w2 = Wt + 13 * 16384 + (long)l16 * 128 + kg * 8;
#pragma unroll
    for (int kb = 0; kb < 4; ++kb)
#pragma unroll
        for (int nt = 0; nt < 4; ++nt) {
            bf8_t b = *(const bf8_t*)(w2 + nt * 16 * 128 + kb * 32);
            acc2[0][nt] = __builtin_amdgcn_mfma_f32_16x16x32_bf16(h2[0][kb], b, acc2[0][nt], 0, 0, 0);
            acc2[1][nt] = __builtin_amdgcn_mfma_f32_16x16x32_bf16(h2[1][kb], b, acc2[1][nt], 0, 0, 0);
        }
#pragma unroll
    for (int mt = 0; mt < 2; ++mt)
#pragma unroll
        for (int nt = 0; nt < 4; ++nt)
#pragma unroll
            for (int r = 0; r < 4; ++r) {
                long row = row0 + mt * 16 + kg * 4 + r;
                int col = nt * 16 + l16;
                out[row * DOUT + col] = acc2[mt][nt][r] + b2[col];
            }
}

// ------------------------------------------------------------------ launch
extern "C" void kernel_launch(void* const* d_in, const int* in_sizes, int n_in,
                              void* d_out, int out_size, void* d_ws, size_t ws_size,
                              hipStream_t stream) {
    const float* x      = (const float*)d_in[0];
    const int*   subadj = (const int*)d_in[1];
    const float* adj    = (const float*)d_in[2];
    const float* gcn_W  = (const float*)d_in[3];
    const float* gcn_b  = (const float*)d_in[4];
    const float* lin_W1 = (const float*)d_in[5];
    const float* lin_b1 = (const float*)d_in[6];
    const float* lin_W2 = (const float*)d_in[7];
    const float* lin_b2 = (const float*)d_in[8];
    float* out = (float*)d_out;

    const int* e_src = subadj;
    const int* e_dst = subadj + NEDGES;

    char* w = (char*)d_ws;
    int*      whist = (int*)w;      w += (size_t)65536 * 4;
    int*      bbase = (int*)w;      w += (size_t)260 * 4;
    int*      offs  = (int*)w;      w += (size_t)65540 * 4;
    float*    dinv  = (float*)w;    w += (size_t)65536 * 4;
    unsigned* tmp   = (unsigned*)w; w += (size_t)NEDGES * 4;
    unsigned short* csr16 = (unsigned short*)w; w += (size_t)NEDGES * 2;
    unsigned short* Ab  = (unsigned short*)w; w += (size_t)3 * 4096 * 2;
    unsigned short* Xbf = (unsigned short*)w; w += (size_t)NNODES * D * 2;
    unsigned short* Ybf = (unsigned short*)w; w += (size_t)NNODES * D * 2;   // 4 chunk planes
    unsigned short* Wt  = (unsigned short*)w; w += (size_t)14 * 16384 * 2;

    k_bhist<<<256, 256, 0, stream>>>(e_dst, whist);
    k_bscan<<<1, 256, 0, stream>>>(whist, bbase);
    k_bscatter<<<256, 256, 0, stream>>>(e_src, e_dst, bbase, whist, tmp);
    k_bcsr<<<256, 256, 0, stream>>>(tmp, bbase, offs, dinv, csr16);
    k_setup<<<897, 256, 0, stream>>>(adj, Ab, gcn_W, lin_W1, lin_W2, Wt);

    for (int li = 0; li < 3; ++li) {
        if (li == 0)
            k_layer<true><<<MSUB, 256, 0, stream>>>(nullptr, x, Ab, Wt, dinv, Ybf);
        else
            k_layer<false><<<MSUB, 256, 0, stream>>>(Xbf, nullptr, Ab,
                                                     Wt + (size_t)li * 4 * 16384, dinv, Ybf);
        k_prop<<<NNODES, 256, 0, stream>>>(Ybf, offs, csr16, dinv,
                                           gcn_b + (size_t)li * 512, Xbf);
    }
    k_mlp<<<NNODES / 128, 256, 0, stream>>>(Xbf, Wt, lin_b1, lin_b2, out);
}

// Round 5
// 502.914 us; speedup vs baseline: 1.4282x; 1.4282x over previous
//
#include <hip/hip_runtime.h>

#define NMETA 64
#define MSUB 1024
#define NNODES 65536          // NMETA*MSUB
#define D 128
#define DOUT 64
#define NEDGES 1048576
#define COLS 131072           // MSUB*D
#define BCAP 5120             // LDS capacity per bucket (mean 4096, sigma ~64)

typedef __attribute__((ext_vector_type(8))) short bf8_t;   // 8 bf16 = 4 VGPRs
typedef __attribute__((ext_vector_type(4))) float f4_t;
typedef __attribute__((ext_vector_type(2))) float f2_t;    // -> v_pk_fma_f32

__device__ inline unsigned short bfr(float x) {            // fp32 -> bf16 RNE
    unsigned u = __builtin_bit_cast(unsigned, x);
    u += 0x7fffu + ((u >> 16) & 1u);
    return (unsigned short)(u >> 16);
}
__device__ inline float b2f(unsigned short h) {
    return __builtin_bit_cast(float, (unsigned)h << 16);
}
__device__ inline f2_t up2(unsigned u) {                   // 2 bf16 -> 2 fp32
    f2_t r;
    r[0] = __builtin_bit_cast(float, u << 16);
    r[1] = __builtin_bit_cast(float, u & 0xffff0000u);
    return r;
}

// ------------------------------------------------------- CSR via 256-bucket radix
__global__ __launch_bounds__(256) void k_bhist(const int* __restrict__ dst,
                                               int* __restrict__ whist) {
    __shared__ int c[256];
    int t = threadIdx.x, w = blockIdx.x;
    c[t] = 0;
    __syncthreads();
    const int* dp = dst + w * 4096;
    for (int k = 0; k < 16; ++k) atomicAdd(&c[dp[k * 256 + t] >> 8], 1);
    __syncthreads();
    whist[t * 256 + w] = c[t];
}

__global__ __launch_bounds__(256) void k_bscan(int* __restrict__ whist,
                                               int* __restrict__ bbase) {
    __shared__ int sh[256];
    int t = threadIdx.x;
    int run = 0;
    for (int w = 0; w < 256; ++w) {
        int v = whist[t * 256 + w];
        whist[t * 256 + w] = run;
        run += v;
    }
    sh[t] = run;
    __syncthreads();
    for (int d = 1; d < 256; d <<= 1) {
        int x = (t >= d) ? sh[t - d] : 0;
        __syncthreads();
        sh[t] += x;
        __syncthreads();
    }
    bbase[t] = sh[t] - run;
    if (t == 255) bbase[256] = NEDGES;
}

__global__ __launch_bounds__(256) void k_bscatter(const int* __restrict__ src,
                                                  const int* __restrict__ dst,
                                                  const int* __restrict__ bbase,
                                                  const int* __restrict__ whist,
                                                  unsigned* __restrict__ tmp) {
    __shared__ int cur[256];
    __shared__ int base[256];
    int t = threadIdx.x, w = blockIdx.x;
    cur[t] = 0;
    base[t] = bbase[t] + whist[t * 256 + w];
    __syncthreads();
    const int* dp = dst + w * 4096;
    const int* sp = src + w * 4096;
    for (int k = 0; k < 16; ++k) {
        int d = dp[k * 256 + t], s = sp[k * 256 + t];
        int b = d >> 8;
        int lr = atomicAdd(&cur[b], 1);
        tmp[base[b] + lr] = ((unsigned)(d & 255) << 16) | (unsigned)s;
    }
}

// builds per-dst lists, then SORTS each dst's list ascending by source id so
// that k_prop's concurrent waves sweep Y in a narrow moving band (L2-resident).
__global__ __launch_bounds__(256) void k_bcsr(const unsigned* __restrict__ tmp,
                                              const int* __restrict__ bbase,
                                              int* __restrict__ offs,
                                              float* __restrict__ dinv,
                                              unsigned short* __restrict__ csr16) {
    __shared__ unsigned pairs[BCAP];
    __shared__ unsigned short image[BCAP];
    __shared__ int cnt[256], cur[256], sh[256];
    int t = threadIdx.x, b = blockIdx.x;
    int base = bbase[b], n = bbase[b + 1] - base;
    for (int i = t; i < n; i += 256) pairs[i] = tmp[base + i];
    cnt[t] = 0;
    __syncthreads();
    for (int i = t; i < n; i += 256) atomicAdd(&cnt[pairs[i] >> 16], 1);
    __syncthreads();
    int c = cnt[t];
    sh[t] = c;
    __syncthreads();
    for (int d = 1; d < 256; d <<= 1) {
        int x = (t >= d) ? sh[t - d] : 0;
        __syncthreads();
        sh[t] += x;
        __syncthreads();
    }
    int excl = sh[t] - c;
    cur[t] = excl;
    offs[b * 256 + t] = base + excl;
    dinv[b * 256 + t] = rsqrtf((float)(c + 1));
    if (b == 255 && t == 255) offs[65536] = NEDGES;
    __syncthreads();
    for (int i = t; i < n; i += 256) {
        unsigned p = pairs[i];
        int pos = atomicAdd(&cur[p >> 16], 1);
        image[pos] = (unsigned short)(p & 0xffffu);
    }
    __syncthreads();
    // thread t owns image[excl .. excl+c): insertion-sort by source id
    {
        int s0 = excl, s1 = excl + c;
        for (int i = s0 + 1; i < s1; ++i) {
            unsigned short key = image[i];
            int j = i - 1;
            while (j >= s0 && image[j] > key) { image[j + 1] = image[j]; --j; }
            image[j + 1] = key;
        }
    }
    __syncthreads();
    for (int i = t; i < n; i += 256) csr16[base + i] = image[i];
}

// --------------------------------------------- setup: adjpow + cvt_w (x handled by layer 0)
__global__ __launch_bounds__(256) void k_setup(const float* __restrict__ A,
                                               unsigned short* __restrict__ Ab,
                                               const float* __restrict__ gcnW,
                                               const float* __restrict__ W1,
                                               const float* __restrict__ W2,
                                               unsigned short* __restrict__ Wt) {
    int blk = blockIdx.x, t = threadIdx.x;
    if (blk == 0) {
        __shared__ float As[4096];
        __shared__ float Bs[4096];
        for (int q = 0; q < 16; ++q) As[t + 256 * q] = A[t + 256 * q];
        __syncthreads();
        for (int q = 0; q < 16; ++q) {
            int idx = t + 256 * q;
            int n = idx >> 6, j = idx & 63;
            Ab[idx] = bfr(As[idx]);
            float acc = 0.f;
            for (int k = 0; k < 64; ++k) acc += As[n * 64 + k] * As[k * 64 + j];
            Bs[idx] = acc;
            Ab[4096 + idx] = bfr(acc);
        }
        __syncthreads();
        for (int q = 0; q < 16; ++q) {
            int idx = t + 256 * q;
            int n = idx >> 6, j = idx & 63;
            float acc = 0.f;
            for (int k = 0; k < 64; ++k) acc += Bs[n * 64 + k] * As[k * 64 + j];
            Ab[8192 + idx] = bfr(acc);
        }
    } else {
        int b2 = blk - 1;
        int m = b2 >> 6;
        int idx = (b2 & 63) * 256 + t;
        const float* src;
        int N = 128;
        if (m < 12)       src = gcnW + m * 16384;
        else if (m == 12) src = W1;
        else { src = W2; N = 64; if (idx >= 8192) return; }
        int n = idx >> 7, k = idx & 127;
        Wt[m * 16384 + idx] = bfr(src[k * N + n]);
    }
}

// ------------------------------------------------- fused layer: mix + gemm
// One block per sub-node m. Y[:,m,:] = dinv ⊙ sum_z A_z @ (X[:,m,:] @ W_z), A_0 = I.
// Output rows are PRE-SCALED by dinv[node] so k_prop gathers are a pure sum.
#define TS 130
template <bool INF32>
__global__ __launch_bounds__(256) void k_layer(const unsigned short* __restrict__ X,
                                               const float* __restrict__ Xf,
                                               const unsigned short* __restrict__ Ab,
                                               const unsigned short* __restrict__ Wt4,
                                               const float* __restrict__ dinv,
                                               unsigned short* __restrict__ Y) {
    __shared__ unsigned short LB[3 * 64 * TS];   // 48.75 KB; aliased X stage first
    __shared__ float dsh[64];
    int t = threadIdx.x;
    int m = blockIdx.x;
    int wave = t >> 6, lane = t & 63;
    int l16 = lane & 15, kg = lane >> 4;
    int c0 = wave * 32;

    if (t < 64) dsh[t] = dinv[(long)t * MSUB + m];

    // stage X[:, m, :] as [row][128] (row stride 256B, 16B-aligned)
#pragma unroll
    for (int it = 0; it < 4; ++it) {
        int slot = it * 256 + t;
        int row = slot >> 4, ch = slot & 15;
        if (INF32) {
            const float* xp = Xf + ((long)row * MSUB + m) * D + ch * 8;
            float4 va = *(const float4*)xp;
            float4 vb = *(const float4*)(xp + 4);
            uint4 pk;
            pk.x = ((unsigned)bfr(va.y) << 16) | bfr(va.x);
            pk.y = ((unsigned)bfr(va.w) << 16) | bfr(va.z);
            pk.z = ((unsigned)bfr(vb.y) << 16) | bfr(vb.x);
            pk.w = ((unsigned)bfr(vb.w) << 16) | bfr(vb.z);
            *(uint4*)&LB[row * 128 + ch * 8] = pk;
        } else {
            *(uint4*)&LB[row * 128 + ch * 8] =
                *(const uint4*)(X + ((long)row * MSUB + m) * D + ch * 8);
        }
    }
    __syncthreads();

    // snapshot A-operand fragments of X_m (all 4 m-tiles, full K=128)
    bf8_t xa[4][4];
#pragma unroll
    for (int mt = 0; mt < 4; ++mt)
#pragma unroll
        for (int kb = 0; kb < 4; ++kb)
            xa[mt][kb] = *(const bf8_t*)&LB[(mt * 16 + l16) * 128 + kb * 32 + kg * 8];
    __syncthreads();   // everyone done reading X stage before T overwrites it

    f4_t zero4 = {0.f, 0.f, 0.f, 0.f};

    // phase 1a: T_0 = X_m @ W_0 -> registers
    f4_t accT0[4][2];
#pragma unroll
    for (int mt = 0; mt < 4; ++mt)
#pragma unroll
        for (int nt = 0; nt < 2; ++nt) accT0[mt][nt] = zero4;
#pragma unroll
    for (int kb = 0; kb < 4; ++kb)
#pragma unroll
        for (int nt = 0; nt < 2; ++nt) {
            bf8_t b = *(const bf8_t*)(Wt4 + (long)(c0 + nt * 16 + l16) * 128 +
                                      kb * 32 + kg * 8);
#pragma unroll
            for (int mt = 0; mt < 4; ++mt)
                accT0[mt][nt] = __builtin_amdgcn_mfma_f32_16x16x32_bf16(
                    xa[mt][kb], b, accT0[mt][nt], 0, 0, 0);
        }

    // phase 1b: T_z = X_m @ W_z (z=1..3) -> LDS (bf16), this wave's 32 cols
#pragma unroll
    for (int z = 1; z < 4; ++z) {
        f4_t acc[4][2];
#pragma unroll
        for (int mt = 0; mt < 4; ++mt)
#pragma unroll
            for (int nt = 0; nt < 2; ++nt) acc[mt][nt] = zero4;
        const unsigned short* wp = Wt4 + z * 16384;
#pragma unroll
        for (int kb = 0; kb < 4; ++kb)
#pragma unroll
            for (int nt = 0; nt < 2; ++nt) {
                bf8_t b = *(const bf8_t*)(wp + (long)(c0 + nt * 16 + l16) * 128 +
                                          kb * 32 + kg * 8);
#pragma unroll
                for (int mt = 0; mt < 4; ++mt)
                    acc[mt][nt] = __builtin_amdgcn_mfma_f32_16x16x32_bf16(
                        xa[mt][kb], b, acc[mt][nt], 0, 0, 0);
            }
#pragma unroll
        for (int mt = 0; mt < 4; ++mt)
#pragma unroll
            for (int nt = 0; nt < 2; ++nt)
#pragma unroll
                for (int r = 0; r < 4; ++r)
                    LB[((z - 1) * 64 + mt * 16 + kg * 4 + r) * TS +
                       c0 + nt * 16 + l16] = bfr(acc[mt][nt][r]);
    }
    // no barrier: each wave reads only its own column slab of T

    // phase 2: Y_slab = T_0 + sum_i A_i @ T_i
    f4_t acc2[4][2];
#pragma unroll
    for (int mt = 0; mt < 4; ++mt)
#pragma unroll
        for (int nt = 0; nt < 2; ++nt) acc2[mt][nt] = zero4;
#pragma unroll
    for (int i = 0; i < 3; ++i)
#pragma unroll
        for (int kb = 0; kb < 2; ++kb) {
            bf8_t af[4];
#pragma unroll
            for (int mt = 0; mt < 4; ++mt)
                af[mt] = *(const bf8_t*)(Ab + i * 4096 + (mt * 16 + l16) * 64 +
                                         kb * 32 + kg * 8);
#pragma unroll
            for (int nt = 0; nt < 2; ++nt) {
                bf8_t b;
#pragma unroll
                for (int jj = 0; jj < 8; ++jj)
                    b[jj] = (short)LB[(i * 64 + kb * 32 + kg * 8 + jj) * TS +
                                      c0 + nt * 16 + l16];
#pragma unroll
                for (int mt = 0; mt < 4; ++mt)
                    acc2[mt][nt] = __builtin_amdgcn_mfma_f32_16x16x32_bf16(
                        af[mt], b, acc2[mt][nt], 0, 0, 0);
            }
        }

#pragma unroll
    for (int mt = 0; mt < 4; ++mt)
#pragma unroll
        for (int nt = 0; nt < 2; ++nt)
#pragma unroll
            for (int r = 0; r < 4; ++r) {
                int row = mt * 16 + kg * 4 + r;
                int col = c0 + nt * 16 + l16;
                float v = (acc2[mt][nt][r] + accT0[mt][nt][r]) * dsh[row];
                Y[((long)row * MSUB + m) * D + col] = bfr(v);
            }
}

// -------------------------------------------------------------- propagation
// Proven R1 shape: one dst per wave, 4 edge slots x 16 col-lanes (16B each,
// full 256B rows), 4 edges in flight per slot pair. Edge lists are
// SOURCE-SORTED so concurrent waves sweep Y monotonically (narrow L2 band).
__global__ __launch_bounds__(256) void k_prop(const unsigned short* __restrict__ Y,
                                              const int* __restrict__ offs,
                                              const unsigned short* __restrict__ csr,
                                              const float* __restrict__ dinv,
                                              const float* __restrict__ bias4,
                                              unsigned short* __restrict__ Xout) {
    int wid = threadIdx.x >> 6;
    int lane = threadIdx.x & 63;
    int q = lane >> 4;
    int l = lane & 15;
    int v = blockIdx.x * 4 + wid;
    const uint4* Y4 = (const uint4*)Y;
    int e0 = offs[v], e1 = offs[v + 1];
    f2_t acc2[4];
#pragma unroll
    for (int k = 0; k < 4; ++k) acc2[k] = (f2_t){0.f, 0.f};

    int e = e0 + q;
    for (; e + 4 < e1; e += 8) {
        int u0 = csr[e], u1 = csr[e + 4];
        uint4 y0 = Y4[(long)u0 * 16 + l];
        uint4 y1 = Y4[(long)u1 * 16 + l];
        acc2[0] += up2(y0.x) + up2(y1.x);
        acc2[1] += up2(y0.y) + up2(y1.y);
        acc2[2] += up2(y0.z) + up2(y1.z);
        acc2[3] += up2(y0.w) + up2(y1.w);
    }
    if (e < e1) {
        int u = csr[e];
        uint4 y = Y4[(long)u * 16 + l];
        acc2[0] += up2(y.x);
        acc2[1] += up2(y.y);
        acc2[2] += up2(y.z);
        acc2[3] += up2(y.w);
    }
    float acc[8];
#pragma unroll
    for (int k = 0; k < 4; ++k) { acc[2 * k] = acc2[k][0]; acc[2 * k + 1] = acc2[k][1]; }
#pragma unroll
    for (int k = 0; k < 8; ++k) {
        acc[k] += __shfl_xor(acc[k], 32, 64);
        acc[k] += __shfl_xor(acc[k], 16, 64);
    }
    if (q == 0) {
        float dv = dinv[v];
        uint4 s = Y4[(long)v * 16 + l];           // pre-scaled self row
        f2_t s2[4] = {up2(s.x), up2(s.y), up2(s.z), up2(s.w)};
        float bs[8];
#pragma unroll
        for (int k = 0; k < 8; ++k) bs[k] = 0.f;
#pragma unroll
        for (int p = 0; p < 4; ++p) {
            float4 blo = *(const float4*)(bias4 + p * 128 + l * 8);
            float4 bhi = *(const float4*)(bias4 + p * 128 + l * 8 + 4);
            bs[0] += blo.x; bs[1] += blo.y; bs[2] += blo.z; bs[3] += blo.w;
            bs[4] += bhi.x; bs[5] += bhi.y; bs[6] += bhi.z; bs[7] += bhi.w;
        }
        unsigned r[8];
#pragma unroll
        for (int k = 0; k < 8; ++k) {
            float sf = s2[k / 2][k % 2];
            r[k] = bfr(fmaxf(dv * (acc[k] + sf) + bs[k], 0.f));
        }
        uint4 pk;
        pk.x = (r[1] << 16) | r[0];
        pk.y = (r[3] << 16) | r[2];
        pk.z = (r[5] << 16) | r[4];
        pk.w = (r[7] << 16) | r[6];
        ((uint4*)Xout)[(long)v * 16 + l] = pk;
    }
}

// ---------------------------------------------------- fused MLP: relu(X@W1+b1)@W2+b2
// 128 rows/block, H kept in LDS (stride 136 shorts: b128 reads <=2-way).
// Each wave computes its own 32 H rows then consumes them -> no barriers.
#define HST 136
__global__ __launch_bounds__(256) void k_mlp(const unsigned short* __restrict__ X,
                                             const unsigned short* __restrict__ Wt, // +12*16384 = W1t, +13*16384 = W2t
                                             const float* __restrict__ b1,
                                             const float* __restrict__ b2,
                                             float* __restrict__ out) {
    __shared__ unsigned short H[128 * HST];      // 34.8 KB
    int wave = threadIdx.x >> 6, lane = threadIdx.x & 63;
    int l16 = lane & 15, kg = lane >> 4;
    long row0 = (long)blockIdx.x * 128 + wave * 32;
    int hb = wave * 32 * HST;

    bf8_t a[2][4];
    const unsigned short* xp = X + row0 * 128 + kg * 8;
#pragma unroll
    for (int kb = 0; kb < 4; ++kb) {
        a[0][kb] = *(const bf8_t*)(xp + (long)l16 * 128 + kb * 32);
        a[1][kb] = *(const bf8_t*)(xp + (long)(l16 + 16) * 128 + kb * 32);
    }
    f4_t zero4 = {0.f, 0.f, 0.f, 0.f};
    f4_t acc[2][8];
#pragma unroll
    for (int mt = 0; mt < 2; ++mt)
#pragma unroll
        for (int nt = 0; nt < 8; ++nt) acc[mt][nt] = zero4;

    const unsigned short* wp = Wt + 12 * 16384 + (long)l16 * 128 + kg * 8;
#pragma unroll
    for (int kb = 0; kb < 4; ++kb)
#pragma unroll
        for (int nt = 0; nt < 8; ++nt) {
            bf8_t b = *(const bf8_t*)(wp + nt * 16 * 128 + kb * 32);
            acc[0][nt] = __builtin_amdgcn_mfma_f32_16x16x32_bf16(a[0][kb], b, acc[0][nt], 0, 0, 0);
            acc[1][nt] = __builtin_amdgcn_mfma_f32_16x16x32_bf16(a[1][kb], b, acc[1][nt], 0, 0, 0);
        }

    // epilogue 1: H = relu(acc + b1) -> LDS (wave-local rows)
#pragma unroll
    for (int nt = 0; nt < 8; ++nt) {
        float bv = b1[nt * 16 + l16];
#pragma unroll
        for (int mt = 0; mt < 2; ++mt)
#pragma unroll
            for (int r = 0; r < 4; ++r) {
                int row = mt * 16 + kg * 4 + r;
                H[hb + row * HST + nt * 16 + l16] = bfr(fmaxf(acc[mt][nt][r] + bv, 0.f));
            }
    }

    // second GEMM: out = H @ W2 + b2  (A-frags from LDS, same-wave rows)
    bf8_t h2[2][4];
#pragma unroll
    for (int kb = 0; kb < 4; ++kb) {
        h2[0][kb] = *(const bf8_t*)&H[hb + l16 * HST + kb * 32 + kg * 8];
        h2[1][kb] = *(const bf8_t*)&H[hb + (l16 + 16) * HST + kb * 32 + kg * 8];
    }
    f4_t acc2[2][4];
#pragma unroll
    for (int mt = 0; mt < 2; ++mt)
#pragma unroll
        for (int nt = 0; nt < 4; ++nt) acc2[mt][nt] = zero4;
    const unsigned short* w2 = Wt + 13 * 16384 + (long)l16 * 128 + kg * 8;
#pragma unroll
    for (int kb = 0; kb < 4; ++kb)
#pragma unroll
        for (int nt = 0; nt < 4; ++nt) {
            bf8_t b = *(const bf8_t*)(w2 + nt * 16 * 128 + kb * 32);
            acc2[0][nt] = __builtin_amdgcn_mfma_f32_16x16x32_bf16(h2[0][kb], b, acc2[0][nt], 0, 0, 0);
            acc2[1][nt] = __builtin_amdgcn_mfma_f32_16x16x32_bf16(h2[1][kb], b, acc2[1][nt], 0, 0, 0);
        }
#pragma unroll
    for (int mt = 0; mt < 2; ++mt)
#pragma unroll
        for (int nt = 0; nt < 4; ++nt)
#pragma unroll
            for (int r = 0; r < 4; ++r) {
                long row = row0 + mt * 16 + kg * 4 + r;
                int col = nt * 16 + l16;
                out[row * DOUT + col] = acc2[mt][nt][r] + b2[col];
            }
}

// ------------------------------------------------------------------ launch
extern "C" void kernel_launch(void* const* d_in, const int* in_sizes, int n_in,
                              void* d_out, int out_size, void* d_ws, size_t ws_size,
                              hipStream_t stream) {
    const float* x      = (const float*)d_in[0];
    const int*   subadj = (const int*)d_in[1];
    const float* adj    = (const float*)d_in[2];
    const float* gcn_W  = (const float*)d_in[3];
    const float* gcn_b  = (const float*)d_in[4];
    const float* lin_W1 = (const float*)d_in[5];
    const float* lin_b1 = (const float*)d_in[6];
    const float* lin_W2 = (const float*)d_in[7];
    const float* lin_b2 = (const float*)d_in[8];
    float* out = (float*)d_out;

    const int* e_src = subadj;
    const int* e_dst = subadj + NEDGES;

    char* w = (char*)d_ws;
    int*      whist = (int*)w;      w += (size_t)65536 * 4;
    int*      bbase = (int*)w;      w += (size_t)260 * 4;
    int*      offs  = (int*)w;      w += (size_t)65540 * 4;
    float*    dinv  = (float*)w;    w += (size_t)65536 * 4;
    unsigned* tmp   = (unsigned*)w; w += (size_t)NEDGES * 4;
    unsigned short* csr16 = (unsigned short*)w; w += (size_t)NEDGES * 2;
    unsigned short* Ab  = (unsigned short*)w; w += (size_t)3 * 4096 * 2;
    unsigned short* Xbf = (unsigned short*)w; w += (size_t)NNODES * D * 2;
    unsigned short* Ybf = (unsigned short*)w; w += (size_t)NNODES * D * 2;
    unsigned short* Wt  = (unsigned short*)w; w += (size_t)14 * 16384 * 2;

    k_bhist<<<256, 256, 0, stream>>>(e_dst, whist);
    k_bscan<<<1, 256, 0, stream>>>(whist, bbase);
    k_bscatter<<<256, 256, 0, stream>>>(e_src, e_dst, bbase, whist, tmp);
    k_bcsr<<<256, 256, 0, stream>>>(tmp, bbase, offs, dinv, csr16);
    k_setup<<<897, 256, 0, stream>>>(adj, Ab, gcn_W, lin_W1, lin_W2, Wt);

    for (int li = 0; li < 3; ++li) {
        if (li == 0)
            k_layer<true><<<MSUB, 256, 0, stream>>>(nullptr, x, Ab, Wt, dinv, Ybf);
        else
            k_layer<false><<<MSUB, 256, 0, stream>>>(Xbf, nullptr, Ab,
                                                     Wt + (size_t)li * 4 * 16384, dinv, Ybf);
        k_prop<<<NNODES / 4, 256, 0, stream>>>(Ybf, offs, csr16, dinv,
                                               gcn_b + (size_t)li * 512, Xbf);
    }
    k_mlp<<<NNODES / 128, 256, 0, stream>>>(Xbf, Wt, lin_b1, lin_b2, out);
}

// Round 7
// 483.583 us; speedup vs baseline: 1.4853x; 1.0400x over previous
//
#include <hip/hip_runtime.h>

#define NMETA 64
#define MSUB 1024
#define NNODES 65536          // NMETA*MSUB
#define D 128
#define DOUT 64
#define NEDGES 1048576
#define COLS 131072           // MSUB*D
#define BCAP 5120             // LDS capacity per bucket (mean 4096, sigma ~64)

typedef __attribute__((ext_vector_type(8))) short bf8_t;   // 8 bf16 = 4 VGPRs
typedef __attribute__((ext_vector_type(4))) float f4_t;
typedef __attribute__((ext_vector_type(2))) float f2_t;    // -> v_pk_fma_f32
typedef __attribute__((ext_vector_type(2))) unsigned ui2_t; // 8B LDS write

__device__ inline unsigned short bfr(float x) {            // fp32 -> bf16 RNE
    unsigned u = __builtin_bit_cast(unsigned, x);
    u += 0x7fffu + ((u >> 16) & 1u);
    return (unsigned short)(u >> 16);
}
__device__ inline float b2f(unsigned short h) {
    return __builtin_bit_cast(float, (unsigned)h << 16);
}
__device__ inline f2_t up2(unsigned u) {                   // 2 bf16 -> 2 fp32
    f2_t r;
    r[0] = __builtin_bit_cast(float, u << 16);
    r[1] = __builtin_bit_cast(float, u & 0xffff0000u);
    return r;
}

// ------------------------------------------------------- CSR via 256-bucket radix
__global__ __launch_bounds__(256) void k_bhist(const int* __restrict__ dst,
                                               int* __restrict__ whist) {
    __shared__ int c[256];
    int t = threadIdx.x, w = blockIdx.x;
    c[t] = 0;
    __syncthreads();
    const int* dp = dst + w * 4096;
    for (int k = 0; k < 16; ++k) atomicAdd(&c[dp[k * 256 + t] >> 8], 1);
    __syncthreads();
    whist[t * 256 + w] = c[t];
}

__global__ __launch_bounds__(256) void k_bscan(int* __restrict__ whist,
                                               int* __restrict__ bbase) {
    __shared__ int sh[256];
    int t = threadIdx.x;
    int run = 0;
    for (int w = 0; w < 256; ++w) {
        int v = whist[t * 256 + w];
        whist[t * 256 + w] = run;
        run += v;
    }
    sh[t] = run;
    __syncthreads();
    for (int d = 1; d < 256; d <<= 1) {
        int x = (t >= d) ? sh[t - d] : 0;
        __syncthreads();
        sh[t] += x;
        __syncthreads();
    }
    bbase[t] = sh[t] - run;
    if (t == 255) bbase[256] = NEDGES;
}

__global__ __launch_bounds__(256) void k_bscatter(const int* __restrict__ src,
                                                  const int* __restrict__ dst,
                                                  const int* __restrict__ bbase,
                                                  const int* __restrict__ whist,
                                                  unsigned* __restrict__ tmp) {
    __shared__ int cur[256];
    __shared__ int base[256];
    int t = threadIdx.x, w = blockIdx.x;
    cur[t] = 0;
    base[t] = bbase[t] + whist[t * 256 + w];
    __syncthreads();
    const int* dp = dst + w * 4096;
    const int* sp = src + w * 4096;
    for (int k = 0; k < 16; ++k) {
        int d = dp[k * 256 + t], s = sp[k * 256 + t];
        int b = d >> 8;
        int lr = atomicAdd(&cur[b], 1);
        tmp[base[b] + lr] = ((unsigned)(d & 255) << 16) | (unsigned)s;
    }
}

// builds per-dst lists, then SORTS each dst's list ascending by source id so
// that k_prop's concurrent waves sweep Y in a narrow moving band (L2-resident).
__global__ __launch_bounds__(256) void k_bcsr(const unsigned* __restrict__ tmp,
                                              const int* __restrict__ bbase,
                                              int* __restrict__ offs,
                                              float* __restrict__ dinv,
                                              unsigned short* __restrict__ csr16) {
    __shared__ unsigned pairs[BCAP];
    __shared__ unsigned short image[BCAP];
    __shared__ int cnt[256], cur[256], sh[256];
    int t = threadIdx.x, b = blockIdx.x;
    int base = bbase[b], n = bbase[b + 1] - base;
    for (int i = t; i < n; i += 256) pairs[i] = tmp[base + i];
    cnt[t] = 0;
    __syncthreads();
    for (int i = t; i < n; i += 256) atomicAdd(&cnt[pairs[i] >> 16], 1);
    __syncthreads();
    int c = cnt[t];
    sh[t] = c;
    __syncthreads();
    for (int d = 1; d < 256; d <<= 1) {
        int x = (t >= d) ? sh[t - d] : 0;
        __syncthreads();
        sh[t] += x;
        __syncthreads();
    }
    int excl = sh[t] - c;
    cur[t] = excl;
    offs[b * 256 + t] = base + excl;
    dinv[b * 256 + t] = rsqrtf((float)(c + 1));
    if (b == 255 && t == 255) offs[65536] = NEDGES;
    __syncthreads();
    for (int i = t; i < n; i += 256) {
        unsigned p = pairs[i];
        int pos = atomicAdd(&cur[p >> 16], 1);
        image[pos] = (unsigned short)(p & 0xffffu);
    }
    __syncthreads();
    // thread t owns image[excl .. excl+c): insertion-sort by source id
    {
        int s0 = excl, s1 = excl + c;
        for (int i = s0 + 1; i < s1; ++i) {
            unsigned short key = image[i];
            int j = i - 1;
            while (j >= s0 && image[j] > key) { image[j + 1] = image[j]; --j; }
            image[j + 1] = key;
        }
    }
    __syncthreads();
    for (int i = t; i < n; i += 256) csr16[base + i] = image[i];
}

// --------------------------------------------- setup: adjpow + cvt_w (x handled by layer 0)
__global__ __launch_bounds__(256) void k_setup(const float* __restrict__ A,
                                               unsigned short* __restrict__ Ab,
                                               const float* __restrict__ gcnW,
                                               const float* __restrict__ W1,
                                               const float* __restrict__ W2,
                                               unsigned short* __restrict__ Wt) {
    int blk = blockIdx.x, t = threadIdx.x;
    if (blk == 0) {
        __shared__ float As[4096];
        __shared__ float Bs[4096];
        for (int q = 0; q < 16; ++q) As[t + 256 * q] = A[t + 256 * q];
        __syncthreads();
        for (int q = 0; q < 16; ++q) {
            int idx = t + 256 * q;
            int n = idx >> 6, j = idx & 63;
            Ab[idx] = bfr(As[idx]);
            float acc = 0.f;
            for (int k = 0; k < 64; ++k) acc += As[n * 64 + k] * As[k * 64 + j];
            Bs[idx] = acc;
            Ab[4096 + idx] = bfr(acc);
        }
        __syncthreads();
        for (int q = 0; q < 16; ++q) {
            int idx = t + 256 * q;
            int n = idx >> 6, j = idx & 63;
            float acc = 0.f;
            for (int k = 0; k < 64; ++k) acc += Bs[n * 64 + k] * As[k * 64 + j];
            Ab[8192 + idx] = bfr(acc);
        }
    } else {
        int b2 = blk - 1;
        int m = b2 >> 6;
        int idx = (b2 & 63) * 256 + t;
        const float* src;
        int N = 128;
        if (m < 12)       src = gcnW + m * 16384;
        else if (m == 12) src = W1;
        else { src = W2; N = 64; if (idx >= 8192) return; }
        int n = idx >> 7, k = idx & 127;
        Wt[m * 16384 + idx] = bfr(src[k * N + n]);
    }
}

// ------------------------------------------------- fused layer: mix + gemm
// One block per sub-node m. Y[:,m,:] = dinv ⊙ sum_z A_z @ (X[:,m,:] @ W_z), A_0 = I.
// Restructured (R6): one z-plane live at a time in a WAVE-PRIVATE 4KB slab,
// stored TRANSPOSED (Tt[col][row], XOR-swizzled) so production is 8x ds_write_b64
// and consumption is aligned ds_read_b128. LDS = 16KB (vs 49KB) -> 2x occupancy.
// The X stage (64 rows x 128, 16KB) aliases the 4 slabs; xa snapshot + barrier
// protects it. acc2 doubles as the T_0 (identity-A) accumulator.
template <bool INF32>
__global__ __launch_bounds__(256) void k_layer(const unsigned short* __restrict__ X,
                                               const float* __restrict__ Xf,
                                               const unsigned short* __restrict__ Ab,
                                               const unsigned short* __restrict__ Wt4,
                                               const float* __restrict__ dinv,
                                               unsigned short* __restrict__ Y) {
    __shared__ unsigned short LB[8192];          // 16 KB: X stage, then 4 wave slabs
    __shared__ float dsh[64];
    int t = threadIdx.x;
    int m = blockIdx.x;
    int wave = t >> 6, lane = t & 63;
    int l16 = lane & 15, kg = lane >> 4;
    int c0 = wave * 32;

    if (t < 64) dsh[t] = dinv[(long)t * MSUB + m];

    // stage X[:, m, :] as [row][128] (row stride 256B, 16B-aligned)
#pragma unroll
    for (int it = 0; it < 4; ++it) {
        int slot = it * 256 + t;
        int row = slot >> 4, ch = slot & 15;
        if (INF32) {
            const float* xp = Xf + ((long)row * MSUB + m) * D + ch * 8;
            float4 va = *(const float4*)xp;
            float4 vb = *(const float4*)(xp + 4);
            uint4 pk;
            pk.x = ((unsigned)bfr(va.y) << 16) | bfr(va.x);
            pk.y = ((unsigned)bfr(va.w) << 16) | bfr(va.z);
            pk.z = ((unsigned)bfr(vb.y) << 16) | bfr(vb.x);
            pk.w = ((unsigned)bfr(vb.w) << 16) | bfr(vb.z);
            *(uint4*)&LB[row * 128 + ch * 8] = pk;
        } else {
            *(uint4*)&LB[row * 128 + ch * 8] =
                *(const uint4*)(X + ((long)row * MSUB + m) * D + ch * 8);
        }
    }
    __syncthreads();

    // snapshot A-operand fragments of X_m (all 4 m-tiles, full K=128)
    bf8_t xa[4][4];
#pragma unroll
    for (int mt = 0; mt < 4; ++mt)
#pragma unroll
        for (int kb = 0; kb < 4; ++kb)
            xa[mt][kb] = *(const bf8_t*)&LB[(mt * 16 + l16) * 128 + kb * 32 + kg * 8];
    __syncthreads();   // everyone done reading X stage before slabs overwrite it

    f4_t zero4 = {0.f, 0.f, 0.f, 0.f};

    // acc2 = T_0 = X_m @ W_0 (identity-A contribution accumulates in place)
    f4_t acc2[4][2];
#pragma unroll
    for (int mt = 0; mt < 4; ++mt)
#pragma unroll
        for (int nt = 0; nt < 2; ++nt) acc2[mt][nt] = zero4;
#pragma unroll
    for (int kb = 0; kb < 4; ++kb)
#pragma unroll
        for (int nt = 0; nt < 2; ++nt) {
            bf8_t b = *(const bf8_t*)(Wt4 + (long)(c0 + nt * 16 + l16) * 128 +
                                      kb * 32 + kg * 8);
#pragma unroll
            for (int mt = 0; mt < 4; ++mt)
                acc2[mt][nt] = __builtin_amdgcn_mfma_f32_16x16x32_bf16(
                    xa[mt][kb], b, acc2[mt][nt], 0, 0, 0);
        }

    // per z: T_z = X_m @ W_z -> wave slab (transposed+swizzled); acc2 += A_z @ T_z
    char* slab = (char*)&LB[wave * 2048];
    const unsigned swz = (unsigned)((l16 & 7) << 4);   // col&7 == l16&7
#pragma unroll
    for (int z = 1; z < 4; ++z) {
        f4_t acc[4][2];
#pragma unroll
        for (int mt = 0; mt < 4; ++mt)
#pragma unroll
            for (int nt = 0; nt < 2; ++nt) acc[mt][nt] = zero4;
        const unsigned short* wp = Wt4 + z * 16384;
#pragma unroll
        for (int kb = 0; kb < 4; ++kb)
#pragma unroll
            for (int nt = 0; nt < 2; ++nt) {
                bf8_t b = *(const bf8_t*)(wp + (long)(c0 + nt * 16 + l16) * 128 +
                                          kb * 32 + kg * 8);
#pragma unroll
                for (int mt = 0; mt < 4; ++mt)
                    acc[mt][nt] = __builtin_amdgcn_mfma_f32_16x16x32_bf16(
                        xa[mt][kb], b, acc[mt][nt], 0, 0, 0);
            }
        // write T_z^T: Tt[col'][row], 4 consecutive rows packed per 8B write
#pragma unroll
        for (int mt = 0; mt < 4; ++mt)
#pragma unroll
            for (int nt = 0; nt < 2; ++nt) {
                unsigned lo = (unsigned)bfr(acc[mt][nt][0]) |
                              ((unsigned)bfr(acc[mt][nt][1]) << 16);
                unsigned hi = (unsigned)bfr(acc[mt][nt][2]) |
                              ((unsigned)bfr(acc[mt][nt][3]) << 16);
                ui2_t pk = {lo, hi};
                unsigned boff =
                    (unsigned)(((nt * 16 + l16) * 64 + mt * 16 + kg * 4) * 2) ^ swz;
                *(ui2_t*)(slab + boff) = pk;
            }
        // consume: acc2 += A_z-fragment @ Tt-fragment (aligned b128 reads)
        int i = z - 1;
#pragma unroll
        for (int kb = 0; kb < 2; ++kb) {
            bf8_t af[4];
#pragma unroll
            for (int mt = 0; mt < 4; ++mt)
                af[mt] = *(const bf8_t*)(Ab + i * 4096 + (mt * 16 + l16) * 64 +
                                         kb * 32 + kg * 8);
#pragma unroll
            for (int nt = 0; nt < 2; ++nt) {
                unsigned boff =
                    (unsigned)(((nt * 16 + l16) * 64 + kb * 32 + kg * 8) * 2) ^ swz;
                bf8_t b = *(const bf8_t*)(slab + boff);
#pragma unroll
                for (int mt = 0; mt < 4; ++mt)
                    acc2[mt][nt] = __builtin_amdgcn_mfma_f32_16x16x32_bf16(
                        af[mt], b, acc2[mt][nt], 0, 0, 0);
            }
        }
    }

#pragma unroll
    for (int mt = 0; mt < 4; ++mt)
#pragma unroll
        for (int nt = 0; nt < 2; ++nt)
#pragma unroll
            for (int r = 0; r < 4; ++r) {
                int row = mt * 16 + kg * 4 + r;
                int col = c0 + nt * 16 + l16;
                float v = acc2[mt][nt][r] * dsh[row];
                Y[((long)row * MSUB + m) * D + col] = bfr(v);
            }
}

// -------------------------------------------------------------- propagation
// Proven R1 shape: one dst per wave, 4 edge slots x 16 col-lanes (16B each,
// full 256B rows), 4 edges in flight per slot pair. Edge lists are
// SOURCE-SORTED so concurrent waves sweep Y monotonically (narrow L2 band).
__global__ __launch_bounds__(256) void k_prop(const unsigned short* __restrict__ Y,
                                              const int* __restrict__ offs,
                                              const unsigned short* __restrict__ csr,
                                              const float* __restrict__ dinv,
                                              const float* __restrict__ bias4,
                                              unsigned short* __restrict__ Xout) {
    int wid = threadIdx.x >> 6;
    int lane = threadIdx.x & 63;
    int q = lane >> 4;
    int l = lane & 15;
    int v = blockIdx.x * 4 + wid;
    const uint4* Y4 = (const uint4*)Y;
    int e0 = offs[v], e1 = offs[v + 1];
    f2_t acc2[4];
#pragma unroll
    for (int k = 0; k < 4; ++k) acc2[k] = (f2_t){0.f, 0.f};

    int e = e0 + q;
    for (; e + 4 < e1; e += 8) {
        int u0 = csr[e], u1 = csr[e + 4];
        uint4 y0 = Y4[(long)u0 * 16 + l];
        uint4 y1 = Y4[(long)u1 * 16 + l];
        acc2[0] += up2(y0.x) + up2(y1.x);
        acc2[1] += up2(y0.y) + up2(y1.y);
        acc2[2] += up2(y0.z) + up2(y1.z);
        acc2[3] += up2(y0.w) + up2(y1.w);
    }
    if (e < e1) {
        int u = csr[e];
        uint4 y = Y4[(long)u * 16 + l];
        acc2[0] += up2(y.x);
        acc2[1] += up2(y.y);
        acc2[2] += up2(y.z);
        acc2[3] += up2(y.w);
    }
    float acc[8];
#pragma unroll
    for (int k = 0; k < 4; ++k) { acc[2 * k] = acc2[k][0]; acc[2 * k + 1] = acc2[k][1]; }
#pragma unroll
    for (int k = 0; k < 8; ++k) {
        acc[k] += __shfl_xor(acc[k], 32, 64);
        acc[k] += __shfl_xor(acc[k], 16, 64);
    }
    if (q == 0) {
        float dv = dinv[v];
        uint4 s = Y4[(long)v * 16 + l];           // pre-scaled self row
        f2_t s2[4] = {up2(s.x), up2(s.y), up2(s.z), up2(s.w)};
        float bs[8];
#pragma unroll
        for (int k = 0; k < 8; ++k) bs[k] = 0.f;
#pragma unroll
        for (int p = 0; p < 4; ++p) {
            float4 blo = *(const float4*)(bias4 + p * 128 + l * 8);
            float4 bhi = *(const float4*)(bias4 + p * 128 + l * 8 + 4);
            bs[0] += blo.x; bs[1] += blo.y; bs[2] += blo.z; bs[3] += blo.w;
            bs[4] += bhi.x; bs[5] += bhi.y; bs[6] += bhi.z; bs[7] += bhi.w;
        }
        unsigned r[8];
#pragma unroll
        for (int k = 0; k < 8; ++k) {
            float sf = s2[k / 2][k % 2];
            r[k] = bfr(fmaxf(dv * (acc[k] + sf) + bs[k], 0.f));
        }
        uint4 pk;
        pk.x = (r[1] << 16) | r[0];
        pk.y = (r[3] << 16) | r[2];
        pk.z = (r[5] << 16) | r[4];
        pk.w = (r[7] << 16) | r[6];
        ((uint4*)Xout)[(long)v * 16 + l] = pk;
    }
}

// ---------------------------------------------------- fused MLP: relu(X@W1+b1)@W2+b2
// 128 rows/block, H kept in LDS (stride 136 shorts: b128 reads <=2-way).
// Each wave computes its own 32 H rows then consumes them -> no barriers.
#define HST 136
__global__ __launch_bounds__(256) void k_mlp(const unsigned short* __restrict__ X,
                                             const unsigned short* __restrict__ Wt, // +12*16384 = W1t, +13*16384 = W2t
                                             const float* __restrict__ b1,
                                             const float* __restrict__ b2,
                                             float* __restrict__ out) {
    __shared__ unsigned short H[128 * HST];      // 34.8 KB
    int wave = threadIdx.x >> 6, lane = threadIdx.x & 63;
    int l16 = lane & 15, kg = lane >> 4;
    long row0 = (long)blockIdx.x * 128 + wave * 32;
    int hb = wave * 32 * HST;

    bf8_t a[2][4];
    const unsigned short* xp = X + row0 * 128 + kg * 8;
#pragma unroll
    for (int kb = 0; kb < 4; ++kb) {
        a[0][kb] = *(const bf8_t*)(xp + (long)l16 * 128 + kb * 32);
        a[1][kb] = *(const bf8_t*)(xp + (long)(l16 + 16) * 128 + kb * 32);
    }
    f4_t zero4 = {0.f, 0.f, 0.f, 0.f};
    f4_t acc[2][8];
#pragma unroll
    for (int mt = 0; mt < 2; ++mt)
#pragma unroll
        for (int nt = 0; nt < 8; ++nt) acc[mt][nt] = zero4;

    const unsigned short* wp = Wt + 12 * 16384 + (long)l16 * 128 + kg * 8;
#pragma unroll
    for (int kb = 0; kb < 4; ++kb)
#pragma unroll
        for (int nt = 0; nt < 8; ++nt) {
            bf8_t b = *(const bf8_t*)(wp + nt * 16 * 128 + kb * 32);
            acc[0][nt] = __builtin_amdgcn_mfma_f32_16x16x32_bf16(a[0][kb], b, acc[0][nt], 0, 0, 0);
            acc[1][nt] = __builtin_amdgcn_mfma_f32_16x16x32_bf16(a[1][kb], b, acc[1][nt], 0, 0, 0);
        }

    // epilogue 1: H = relu(acc + b1) -> LDS (wave-local rows)
#pragma unroll
    for (int nt = 0; nt < 8; ++nt) {
        float bv = b1[nt * 16 + l16];
#pragma unroll
        for (int mt = 0; mt < 2; ++mt)
#pragma unroll
            for (int r = 0; r < 4; ++r) {
                int row = mt * 16 + kg * 4 + r;
                H[hb + row * HST + nt * 16 + l16] = bfr(fmaxf(acc[mt][nt][r] + bv, 0.f));
            }
    }

    // second GEMM: out = H @ W2 + b2  (A-frags from LDS, same-wave rows)
    bf8_t h2[2][4];
#pragma unroll
    for (int kb = 0; kb < 4; ++kb) {
        h2[0][kb] = *(const bf8_t*)&H[hb + l16 * HST + kb * 32 + kg * 8];
        h2[1][kb] = *(const bf8_t*)&H[hb + (l16 + 16) * HST + kb * 32 + kg * 8];
    }
    f4_t acc2[2][4];
#pragma unroll
    for (int mt = 0; mt < 2; ++mt)
#pragma unroll
        for (int nt = 0; nt < 4; ++nt) acc2[mt][nt] = zero4;
    const unsigned short* w2 = Wt + 13 * 16384 + (long)l16 * 128 + kg * 8;
#pragma unroll
    for (int kb = 0; kb < 4; ++kb)
#pragma unroll
        for (int nt = 0; nt < 4; ++nt) {
            bf8_t b = *(const bf8_t*)(w2 + nt * 16 * 128 + kb * 32);
            acc2[0][nt] = __builtin_amdgcn_mfma_f32_16x16x32_bf16(h2[0][kb], b, acc2[0][nt], 0, 0, 0);
            acc2[1][nt] = __builtin_amdgcn_mfma_f32_16x16x32_bf16(h2[1][kb], b, acc2[1][nt], 0, 0, 0);
        }
#pragma unroll
    for (int mt = 0; mt < 2; ++mt)
#pragma unroll
        for (int nt = 0; nt < 4; ++nt)
#pragma unroll
            for (int r = 0; r < 4; ++r) {
                long row = row0 + mt * 16 + kg * 4 + r;
                int col = nt * 16 + l16;
                out[row * DOUT + col] = acc2[mt][nt][r] + b2[col];
            }
}

// ------------------------------------------------------------------ launch
extern "C" void kernel_launch(void* const* d_in, const int* in_sizes, int n_in,
                              void* d_out, int out_size, void* d_ws, size_t ws_size,
                              hipStream_t stream) {
    const float* x      = (const float*)d_in[0];
    const int*   subadj = (const int*)d_in[1];
    const float* adj    = (const float*)d_in[2];
    const float* gcn_W  = (const float*)d_in[3];
    const float* gcn_b  = (const float*)d_in[4];
    const float* lin_W1 = (const float*)d_in[5];
    const float* lin_b1 = (const float*)d_in[6];
    const float* lin_W2 = (const float*)d_in[7];
    const float* lin_b2 = (const float*)d_in[8];
    float* out = (float*)d_out;

    const int* e_src = subadj;
    const int* e_dst = subadj + NEDGES;

    char* w = (char*)d_ws;
    int*      whist = (int*)w;      w += (size_t)65536 * 4;
    int*      bbase = (int*)w;      w += (size_t)260 * 4;
    int*      offs  = (int*)w;      w += (size_t)65540 * 4;
    float*    dinv  = (float*)w;    w += (size_t)65536 * 4;
    unsigned* tmp   = (unsigned*)w; w += (size_t)NEDGES * 4;
    unsigned short* csr16 = (unsigned short*)w; w += (size_t)NEDGES * 2;
    unsigned short* Ab  = (unsigned short*)w; w += (size_t)3 * 4096 * 2;
    unsigned short* Xbf = (unsigned short*)w; w += (size_t)NNODES * D * 2;
    unsigned short* Ybf = (unsigned short*)w; w += (size_t)NNODES * D * 2;
    unsigned short* Wt  = (unsigned short*)w; w += (size_t)14 * 16384 * 2;

    k_bhist<<<256, 256, 0, stream>>>(e_dst, whist);
    k_bscan<<<1, 256, 0, stream>>>(whist, bbase);
    k_bscatter<<<256, 256, 0, stream>>>(e_src, e_dst, bbase, whist, tmp);
    k_bcsr<<<256, 256, 0, stream>>>(tmp, bbase, offs, dinv, csr16);
    k_setup<<<897, 256, 0, stream>>>(adj, Ab, gcn_W, lin_W1, lin_W2, Wt);

    for (int li = 0; li < 3; ++li) {
        if (li == 0)
            k_layer<true><<<MSUB, 256, 0, stream>>>(nullptr, x, Ab, Wt, dinv, Ybf);
        else
            k_layer<false><<<MSUB, 256, 0, stream>>>(Xbf, nullptr, Ab,
                                                     Wt + (size_t)li * 4 * 16384, dinv, Ybf);
        k_prop<<<NNODES / 4, 256, 0, stream>>>(Ybf, offs, csr16, dinv,
                                               gcn_b + (size_t)li * 512, Xbf);
    }
    k_mlp<<<NNODES / 128, 256, 0, stream>>>(Xbf, Wt, lin_b1, lin_b2, out);
}

// Round 8
// 428.461 us; speedup vs baseline: 1.6764x; 1.1287x over previous
//
#include <hip/hip_runtime.h>

#define NMETA 64
#define MSUB 1024
#define NNODES 65536          // NMETA*MSUB
#define D 128
#define DOUT 64
#define NEDGES 1048576
#define COLS 131072           // MSUB*D
#define BCAP 5120             // LDS capacity per bucket (mean 4096, sigma ~64)

typedef __attribute__((ext_vector_type(8))) short bf8_t;   // 8 bf16 = 4 VGPRs
typedef __attribute__((ext_vector_type(4))) float f4_t;
typedef __attribute__((ext_vector_type(2))) float f2_t;    // -> v_pk_fma_f32
typedef __attribute__((ext_vector_type(2))) unsigned ui2_t; // 8B LDS write

__device__ inline unsigned short bfr(float x) {            // fp32 -> bf16 RNE
    unsigned u = __builtin_bit_cast(unsigned, x);
    u += 0x7fffu + ((u >> 16) & 1u);
    return (unsigned short)(u >> 16);
}
__device__ inline float b2f(unsigned short h) {
    return __builtin_bit_cast(float, (unsigned)h << 16);
}
__device__ inline f2_t up2(unsigned u) {                   // 2 bf16 -> 2 fp32
    f2_t r;
    r[0] = __builtin_bit_cast(float, u << 16);
    r[1] = __builtin_bit_cast(float, u & 0xffff0000u);
    return r;
}

// ------------------------------------------------------- CSR via 256-bucket radix
__global__ __launch_bounds__(256) void k_bhist(const int* __restrict__ dst,
                                               int* __restrict__ whist) {
    __shared__ int c[256];
    int t = threadIdx.x, w = blockIdx.x;
    c[t] = 0;
    __syncthreads();
    const int* dp = dst + w * 4096;
    for (int k = 0; k < 16; ++k) atomicAdd(&c[dp[k * 256 + t] >> 8], 1);
    __syncthreads();
    whist[t * 256 + w] = c[t];
}

__global__ __launch_bounds__(256) void k_bscan(int* __restrict__ whist,
                                               int* __restrict__ bbase) {
    __shared__ int sh[256];
    int t = threadIdx.x;
    int run = 0;
    for (int w = 0; w < 256; ++w) {
        int v = whist[t * 256 + w];
        whist[t * 256 + w] = run;
        run += v;
    }
    sh[t] = run;
    __syncthreads();
    for (int d = 1; d < 256; d <<= 1) {
        int x = (t >= d) ? sh[t - d] : 0;
        __syncthreads();
        sh[t] += x;
        __syncthreads();
    }
    bbase[t] = sh[t] - run;
    if (t == 255) bbase[256] = NEDGES;
}

__global__ __launch_bounds__(256) void k_bscatter(const int* __restrict__ src,
                                                  const int* __restrict__ dst,
                                                  const int* __restrict__ bbase,
                                                  const int* __restrict__ whist,
                                                  unsigned* __restrict__ tmp) {
    __shared__ int cur[256];
    __shared__ int base[256];
    int t = threadIdx.x, w = blockIdx.x;
    cur[t] = 0;
    base[t] = bbase[t] + whist[t * 256 + w];
    __syncthreads();
    const int* dp = dst + w * 4096;
    const int* sp = src + w * 4096;
    for (int k = 0; k < 16; ++k) {
        int d = dp[k * 256 + t], s = sp[k * 256 + t];
        int b = d >> 8;
        int lr = atomicAdd(&cur[b], 1);
        tmp[base[b] + lr] = ((unsigned)(d & 255) << 16) | (unsigned)s;
    }
}

__global__ __launch_bounds__(256) void k_bcsr(const unsigned* __restrict__ tmp,
                                              const int* __restrict__ bbase,
                                              int* __restrict__ offs,
                                              float* __restrict__ dinv,
                                              unsigned short* __restrict__ csr16) {
    __shared__ unsigned pairs[BCAP];
    __shared__ unsigned short image[BCAP];
    __shared__ int cnt[256], cur[256], sh[256];
    int t = threadIdx.x, b = blockIdx.x;
    int base = bbase[b], n = bbase[b + 1] - base;
    for (int i = t; i < n; i += 256) pairs[i] = tmp[base + i];
    cnt[t] = 0;
    __syncthreads();
    for (int i = t; i < n; i += 256) atomicAdd(&cnt[pairs[i] >> 16], 1);
    __syncthreads();
    int c = cnt[t];
    sh[t] = c;
    __syncthreads();
    for (int d = 1; d < 256; d <<= 1) {
        int x = (t >= d) ? sh[t - d] : 0;
        __syncthreads();
        sh[t] += x;
        __syncthreads();
    }
    int excl = sh[t] - c;
    cur[t] = excl;
    offs[b * 256 + t] = base + excl;
    dinv[b * 256 + t] = rsqrtf((float)(c + 1));
    if (b == 255 && t == 255) offs[65536] = NEDGES;
    __syncthreads();
    for (int i = t; i < n; i += 256) {
        unsigned p = pairs[i];
        int pos = atomicAdd(&cur[p >> 16], 1);
        image[pos] = (unsigned short)(p & 0xffffu);
    }
    __syncthreads();
    for (int i = t; i < n; i += 256) csr16[base + i] = image[i];
}

// ---------------- setup: adjpow + cvt_w + per-layer bias presum
__global__ __launch_bounds__(256) void k_setup(const float* __restrict__ A,
                                               unsigned short* __restrict__ Ab,
                                               const float* __restrict__ gcnW,
                                               const float* __restrict__ W1,
                                               const float* __restrict__ W2,
                                               const float* __restrict__ gcnB,
                                               unsigned short* __restrict__ Wt,
                                               float* __restrict__ bsum) {
    int blk = blockIdx.x, t = threadIdx.x;
    if (blk == 0) {
        __shared__ float As[4096];
        __shared__ float Bs[4096];
        for (int q = 0; q < 16; ++q) As[t + 256 * q] = A[t + 256 * q];
        __syncthreads();
        for (int q = 0; q < 16; ++q) {
            int idx = t + 256 * q;
            int n = idx >> 6, j = idx & 63;
            Ab[idx] = bfr(As[idx]);
            float acc = 0.f;
            for (int k = 0; k < 64; ++k) acc += As[n * 64 + k] * As[k * 64 + j];
            Bs[idx] = acc;
            Ab[4096 + idx] = bfr(acc);
        }
        __syncthreads();
        for (int q = 0; q < 16; ++q) {
            int idx = t + 256 * q;
            int n = idx >> 6, j = idx & 63;
            float acc = 0.f;
            for (int k = 0; k < 64; ++k) acc += Bs[n * 64 + k] * As[k * 64 + j];
            Ab[8192 + idx] = bfr(acc);
        }
        // bias presum: bsum[li*128 + j] = sum_p gcnB[li*512 + p*128 + j]
        if (t < 128) {
            for (int li = 0; li < 3; ++li) {
                const float* bp = gcnB + li * 512 + t;
                bsum[li * 128 + t] = bp[0] + bp[128] + bp[256] + bp[384];
            }
        }
    } else {
        int b2 = blk - 1;
        int m = b2 >> 6;
        int idx = (b2 & 63) * 256 + t;
        const float* src;
        int N = 128;
        if (m < 12)       src = gcnW + m * 16384;
        else if (m == 12) src = W1;
        else { src = W2; N = 64; if (idx >= 8192) return; }
        int n = idx >> 7, k = idx & 127;
        Wt[m * 16384 + idx] = bfr(src[k * N + n]);
    }
}

// ------------------------------------------------- fused layer: mix + gemm
// One block per sub-node m. Y[:,m,:] = dinv ⊙ sum_z A_z @ (X[:,m,:] @ W_z), A_0 = I.
// R6 structure: one z-plane live at a time in a WAVE-PRIVATE 4KB slab,
// stored TRANSPOSED (Tt[col][row], XOR-swizzled): production = 8x ds_write_b64,
// consumption = aligned ds_read_b128. LDS = 16KB. The X stage aliases the slabs;
// xa snapshot + barrier protects it. acc2 doubles as the T_0 accumulator.
template <bool INF32>
__global__ __launch_bounds__(256) void k_layer(const unsigned short* __restrict__ X,
                                               const float* __restrict__ Xf,
                                               const unsigned short* __restrict__ Ab,
                                               const unsigned short* __restrict__ Wt4,
                                               const float* __restrict__ dinv,
                                               unsigned short* __restrict__ Y) {
    __shared__ unsigned short LB[8192];          // 16 KB: X stage, then 4 wave slabs
    __shared__ float dsh[64];
    int t = threadIdx.x;
    int m = blockIdx.x;
    int wave = t >> 6, lane = t & 63;
    int l16 = lane & 15, kg = lane >> 4;
    int c0 = wave * 32;

    if (t < 64) dsh[t] = dinv[(long)t * MSUB + m];

    // stage X[:, m, :] as [row][128] (row stride 256B, 16B-aligned)
#pragma unroll
    for (int it = 0; it < 4; ++it) {
        int slot = it * 256 + t;
        int row = slot >> 4, ch = slot & 15;
        if (INF32) {
            const float* xp = Xf + ((long)row * MSUB + m) * D + ch * 8;
            float4 va = *(const float4*)xp;
            float4 vb = *(const float4*)(xp + 4);
            uint4 pk;
            pk.x = ((unsigned)bfr(va.y) << 16) | bfr(va.x);
            pk.y = ((unsigned)bfr(va.w) << 16) | bfr(va.z);
            pk.z = ((unsigned)bfr(vb.y) << 16) | bfr(vb.x);
            pk.w = ((unsigned)bfr(vb.w) << 16) | bfr(vb.z);
            *(uint4*)&LB[row * 128 + ch * 8] = pk;
        } else {
            *(uint4*)&LB[row * 128 + ch * 8] =
                *(const uint4*)(X + ((long)row * MSUB + m) * D + ch * 8);
        }
    }
    __syncthreads();

    // snapshot A-operand fragments of X_m (all 4 m-tiles, full K=128)
    bf8_t xa[4][4];
#pragma unroll
    for (int mt = 0; mt < 4; ++mt)
#pragma unroll
        for (int kb = 0; kb < 4; ++kb)
            xa[mt][kb] = *(const bf8_t*)&LB[(mt * 16 + l16) * 128 + kb * 32 + kg * 8];
    __syncthreads();   // everyone done reading X stage before slabs overwrite it

    f4_t zero4 = {0.f, 0.f, 0.f, 0.f};

    // acc2 = T_0 = X_m @ W_0 (identity-A contribution accumulates in place)
    f4_t acc2[4][2];
#pragma unroll
    for (int mt = 0; mt < 4; ++mt)
#pragma unroll
        for (int nt = 0; nt < 2; ++nt) acc2[mt][nt] = zero4;
#pragma unroll
    for (int kb = 0; kb < 4; ++kb)
#pragma unroll
        for (int nt = 0; nt < 2; ++nt) {
            bf8_t b = *(const bf8_t*)(Wt4 + (long)(c0 + nt * 16 + l16) * 128 +
                                      kb * 32 + kg * 8);
#pragma unroll
            for (int mt = 0; mt < 4; ++mt)
                acc2[mt][nt] = __builtin_amdgcn_mfma_f32_16x16x32_bf16(
                    xa[mt][kb], b, acc2[mt][nt], 0, 0, 0);
        }

    // per z: T_z = X_m @ W_z -> wave slab (transposed+swizzled); acc2 += A_z @ T_z
    char* slab = (char*)&LB[wave * 2048];
    const unsigned swz = (unsigned)((l16 & 7) << 4);   // col&7 == l16&7
#pragma unroll
    for (int z = 1; z < 4; ++z) {
        f4_t acc[4][2];
#pragma unroll
        for (int mt = 0; mt < 4; ++mt)
#pragma unroll
            for (int nt = 0; nt < 2; ++nt) acc[mt][nt] = zero4;
        const unsigned short* wp = Wt4 + z * 16384;
#pragma unroll
        for (int kb = 0; kb < 4; ++kb)
#pragma unroll
            for (int nt = 0; nt < 2; ++nt) {
                bf8_t b = *(const bf8_t*)(wp + (long)(c0 + nt * 16 + l16) * 128 +
                                          kb * 32 + kg * 8);
#pragma unroll
                for (int mt = 0; mt < 4; ++mt)
                    acc[mt][nt] = __builtin_amdgcn_mfma_f32_16x16x32_bf16(
                        xa[mt][kb], b, acc[mt][nt], 0, 0, 0);
            }
        // write T_z^T: Tt[col'][row], 4 consecutive rows packed per 8B write
#pragma unroll
        for (int mt = 0; mt < 4; ++mt)
#pragma unroll
            for (int nt = 0; nt < 2; ++nt) {
                unsigned lo = (unsigned)bfr(acc[mt][nt][0]) |
                              ((unsigned)bfr(acc[mt][nt][1]) << 16);
                unsigned hi = (unsigned)bfr(acc[mt][nt][2]) |
                              ((unsigned)bfr(acc[mt][nt][3]) << 16);
                ui2_t pk = {lo, hi};
                unsigned boff =
                    (unsigned)(((nt * 16 + l16) * 64 + mt * 16 + kg * 4) * 2) ^ swz;
                *(ui2_t*)(slab + boff) = pk;
            }
        // consume: acc2 += A_z-fragment @ Tt-fragment (aligned b128 reads)
        int i = z - 1;
#pragma unroll
        for (int kb = 0; kb < 2; ++kb) {
            bf8_t af[4];
#pragma unroll
            for (int mt = 0; mt < 4; ++mt)
                af[mt] = *(const bf8_t*)(Ab + i * 4096 + (mt * 16 + l16) * 64 +
                                         kb * 32 + kg * 8);
#pragma unroll
            for (int nt = 0; nt < 2; ++nt) {
                unsigned boff =
                    (unsigned)(((nt * 16 + l16) * 64 + kb * 32 + kg * 8) * 2) ^ swz;
                bf8_t b = *(const bf8_t*)(slab + boff);
#pragma unroll
                for (int mt = 0; mt < 4; ++mt)
                    acc2[mt][nt] = __builtin_amdgcn_mfma_f32_16x16x32_bf16(
                        af[mt], b, acc2[mt][nt], 0, 0, 0);
            }
        }
    }

#pragma unroll
    for (int mt = 0; mt < 4; ++mt)
#pragma unroll
        for (int nt = 0; nt < 2; ++nt)
#pragma unroll
            for (int r = 0; r < 4; ++r) {
                int row = mt * 16 + kg * 4 + r;
                int col = c0 + nt * 16 + l16;
                float v = acc2[mt][nt][r] * dsh[row];
                Y[((long)row * MSUB + m) * D + col] = bfr(v);
            }
}

// -------------------------------------------------------------- propagation
// Proven R1 shape: one dst per wave, 4 edge slots x 16 col-lanes (16B each,
// full 256B rows), 4 edges in flight. Y rows pre-scaled by dinv -> pure sum.
// bsum = precomputed per-layer bias sum (128 floats).
__global__ __launch_bounds__(256) void k_prop(const unsigned short* __restrict__ Y,
                                              const int* __restrict__ offs,
                                              const unsigned short* __restrict__ csr,
                                              const float* __restrict__ dinv,
                                              const float* __restrict__ bsum,
                                              unsigned short* __restrict__ Xout) {
    int wid = threadIdx.x >> 6;
    int lane = threadIdx.x & 63;
    int q = lane >> 4;
    int l = lane & 15;
    int v = blockIdx.x * 4 + wid;
    const uint4* Y4 = (const uint4*)Y;
    int e0 = offs[v], e1 = offs[v + 1];
    f2_t acc2[4];
#pragma unroll
    for (int k = 0; k < 4; ++k) acc2[k] = (f2_t){0.f, 0.f};

    int e = e0 + q;
    for (; e + 4 < e1; e += 8) {
        int u0 = __builtin_nontemporal_load(csr + e);
        int u1 = __builtin_nontemporal_load(csr + e + 4);
        uint4 y0 = Y4[(long)u0 * 16 + l];
        uint4 y1 = Y4[(long)u1 * 16 + l];
        acc2[0] += up2(y0.x) + up2(y1.x);
        acc2[1] += up2(y0.y) + up2(y1.y);
        acc2[2] += up2(y0.z) + up2(y1.z);
        acc2[3] += up2(y0.w) + up2(y1.w);
    }
    if (e < e1) {
        int u = __builtin_nontemporal_load(csr + e);
        uint4 y = Y4[(long)u * 16 + l];
        acc2[0] += up2(y.x);
        acc2[1] += up2(y.y);
        acc2[2] += up2(y.z);
        acc2[3] += up2(y.w);
    }
    float acc[8];
#pragma unroll
    for (int k = 0; k < 4; ++k) { acc[2 * k] = acc2[k][0]; acc[2 * k + 1] = acc2[k][1]; }
#pragma unroll
    for (int k = 0; k < 8; ++k) {
        acc[k] += __shfl_xor(acc[k], 32, 64);
        acc[k] += __shfl_xor(acc[k], 16, 64);
    }
    if (q == 0) {
        float dv = dinv[v];
        uint4 s = Y4[(long)v * 16 + l];           // pre-scaled self row
        f2_t s2[4] = {up2(s.x), up2(s.y), up2(s.z), up2(s.w)};
        float4 blo = *(const float4*)(bsum + l * 8);
        float4 bhi = *(const float4*)(bsum + l * 8 + 4);
        float bs[8] = {blo.x, blo.y, blo.z, blo.w, bhi.x, bhi.y, bhi.z, bhi.w};
        unsigned r[8];
#pragma unroll
        for (int k = 0; k < 8; ++k) {
            float sf = s2[k / 2][k % 2];
            r[k] = bfr(fmaxf(dv * (acc[k] + sf) + bs[k], 0.f));
        }
        uint4 pk;
        pk.x = (r[1] << 16) | r[0];
        pk.y = (r[3] << 16) | r[2];
        pk.z = (r[5] << 16) | r[4];
        pk.w = (r[7] << 16) | r[6];
        ((uint4*)Xout)[(long)v * 16 + l] = pk;
    }
}

// ---------------------------------------------------- fused MLP: relu(X@W1+b1)@W2+b2
// 128 rows/block, H kept in LDS (stride 136 shorts: b128 reads <=2-way).
// Each wave computes its own 32 H rows then consumes them -> no barriers.
#define HST 136
__global__ __launch_bounds__(256) void k_mlp(const unsigned short* __restrict__ X,
                                             const unsigned short* __restrict__ Wt, // +12*16384 = W1t, +13*16384 = W2t
                                             const float* __restrict__ b1,
                                             const float* __restrict__ b2,
                                             float* __restrict__ out) {
    __shared__ unsigned short H[128 * HST];      // 34.8 KB
    int wave = threadIdx.x >> 6, lane = threadIdx.x & 63;
    int l16 = lane & 15, kg = lane >> 4;
    long row0 = (long)blockIdx.x * 128 + wave * 32;
    int hb = wave * 32 * HST;

    bf8_t a[2][4];
    const unsigned short* xp = X + row0 * 128 + kg * 8;
#pragma unroll
    for (int kb = 0; kb < 4; ++kb) {
        a[0][kb] = *(const bf8_t*)(xp + (long)l16 * 128 + kb * 32);
        a[1][kb] = *(const bf8_t*)(xp + (long)(l16 + 16) * 128 + kb * 32);
    }
    f4_t zero4 = {0.f, 0.f, 0.f, 0.f};
    f4_t acc[2][8];
#pragma unroll
    for (int mt = 0; mt < 2; ++mt)
#pragma unroll
        for (int nt = 0; nt < 8; ++nt) acc[mt][nt] = zero4;

    const unsigned short* wp = Wt + 12 * 16384 + (long)l16 * 128 + kg * 8;
#pragma unroll
    for (int kb = 0; kb < 4; ++kb)
#pragma unroll
        for (int nt = 0; nt < 8; ++nt) {
            bf8_t b = *(const bf8_t*)(wp + nt * 16 * 128 + kb * 32);
            acc[0][nt] = __builtin_amdgcn_mfma_f32_16x16x32_bf16(a[0][kb], b, acc[0][nt], 0, 0, 0);
            acc[1][nt] = __builtin_amdgcn_mfma_f32_16x16x32_bf16(a[1][kb], b, acc[1][nt], 0, 0, 0);
        }

    // epilogue 1: H = relu(acc + b1) -> LDS (wave-local rows)
#pragma unroll
    for (int nt = 0; nt < 8; ++nt) {
        float bv = b1[nt * 16 + l16];
#pragma unroll
        for (int mt = 0; mt < 2; ++mt)
#pragma unroll
            for (int r = 0; r < 4; ++r) {
                int row = mt * 16 + kg * 4 + r;
                H[hb + row * HST + nt * 16 + l16] = bfr(fmaxf(acc[mt][nt][r] + bv, 0.f));
            }
    }

    // second GEMM: out = H @ W2 + b2  (A-frags from LDS, same-wave rows)
    bf8_t h2[2][4];
#pragma unroll
    for (int kb = 0; kb < 4; ++kb) {
        h2[0][kb] = *(const bf8_t*)&H[hb + l16 * HST + kb * 32 + kg * 8];
        h2[1][kb] = *(const bf8_t*)&H[hb + (l16 + 16) * HST + kb * 32 + kg * 8];
    }
    f4_t acc2[2][4];
#pragma unroll
    for (int mt = 0; mt < 2; ++mt)
#pragma unroll
        for (int nt = 0; nt < 4; ++nt) acc2[mt][nt] = zero4;
    const unsigned short* w2 = Wt + 13 * 16384 + (long)l16 * 128 + kg * 8;
#pragma unroll
    for (int kb = 0; kb < 4; ++kb)
#pragma unroll
        for (int nt = 0; nt < 4; ++nt) {
            bf8_t b = *(const bf8_t*)(w2 + nt * 16 * 128 + kb * 32);
            acc2[0][nt] = __builtin_amdgcn_mfma_f32_16x16x32_bf16(h2[0][kb], b, acc2[0][nt], 0, 0, 0);
            acc2[1][nt] = __builtin_amdgcn_mfma_f32_16x16x32_bf16(h2[1][kb], b, acc2[1][nt], 0, 0, 0);
        }
#pragma unroll
    for (int mt = 0; mt < 2; ++mt)
#pragma unroll
        for (int nt = 0; nt < 4; ++nt)
#pragma unroll
            for (int r = 0; r < 4; ++r) {
                long row = row0 + mt * 16 + kg * 4 + r;
                int col = nt * 16 + l16;
                out[row * DOUT + col] = acc2[mt][nt][r] + b2[col];
            }
}

// ------------------------------------------------------------------ launch
extern "C" void kernel_launch(void* const* d_in, const int* in_sizes, int n_in,
                              void* d_out, int out_size, void* d_ws, size_t ws_size,
                              hipStream_t stream) {
    const float* x      = (const float*)d_in[0];
    const int*   subadj = (const int*)d_in[1];
    const float* adj    = (const float*)d_in[2];
    const float* gcn_W  = (const float*)d_in[3];
    const float* gcn_b  = (const float*)d_in[4];
    const float* lin_W1 = (const float*)d_in[5];
    const float* lin_b1 = (const float*)d_in[6];
    const float* lin_W2 = (const float*)d_in[7];
    const float* lin_b2 = (const float*)d_in[8];
    float* out = (float*)d_out;

    const int* e_src = subadj;
    const int* e_dst = subadj + NEDGES;

    char* w = (char*)d_ws;
    int*      whist = (int*)w;      w += (size_t)65536 * 4;
    int*      bbase = (int*)w;      w += (size_t)260 * 4;
    int*      offs  = (int*)w;      w += (size_t)65540 * 4;
    float*    dinv  = (float*)w;    w += (size_t)65536 * 4;
    unsigned* tmp   = (unsigned*)w; w += (size_t)NEDGES * 4;
    unsigned short* csr16 = (unsigned short*)w; w += (size_t)NEDGES * 2;
    unsigned short* Ab  = (unsigned short*)w; w += (size_t)3 * 4096 * 2;
    unsigned short* Xbf = (unsigned short*)w; w += (size_t)NNODES * D * 2;
    unsigned short* Ybf = (unsigned short*)w; w += (size_t)NNODES * D * 2;
    unsigned short* Wt  = (unsigned short*)w; w += (size_t)14 * 16384 * 2;
    float*    bsum  = (float*)w;    w += (size_t)3 * 128 * 4;

    k_bhist<<<256, 256, 0, stream>>>(e_dst, whist);
    k_bscan<<<1, 256, 0, stream>>>(whist, bbase);
    k_bscatter<<<256, 256, 0, stream>>>(e_src, e_dst, bbase, whist, tmp);
    k_bcsr<<<256, 256, 0, stream>>>(tmp, bbase, offs, dinv, csr16);
    k_setup<<<897, 256, 0, stream>>>(adj, Ab, gcn_W, lin_W1, lin_W2, gcn_b,
                                     Wt, bsum);

    for (int li = 0; li < 3; ++li) {
        if (li == 0)
            k_layer<true><<<MSUB, 256, 0, stream>>>(nullptr, x, Ab, Wt, dinv, Ybf);
        else
            k_layer<false><<<MSUB, 256, 0, stream>>>(Xbf, nullptr, Ab,
                                                     Wt + (size_t)li * 4 * 16384, dinv, Ybf);
        k_prop<<<NNODES / 4, 256, 0, stream>>>(Ybf, offs, csr16, dinv,
                                               bsum + (size_t)li * 128, Xbf);
    }
    k_mlp<<<NNODES / 128, 256, 0, stream>>>(Xbf, Wt, lin_b1, lin_b2, out);
}